// Round 11
// baseline (172.206 us; speedup 1.0000x reference)
//
#include <hip/hip_runtime.h>
#include <math.h>

#define NBS 16
#define NL 256
#define ND 512
#define NH 8
#define NDFF 2048
#define NT (NBS*NL)   // 4096 tokens

typedef unsigned short u16;
typedef unsigned int   u32;
typedef __attribute__((ext_vector_type(8))) short bf16x8;  // 8 bf16 = 4 VGPRs
typedef __attribute__((ext_vector_type(4))) float f32x4;

__device__ __forceinline__ u16 f2b(float f){
  u32 u = __float_as_uint(f);
  u32 r = u + 0x7FFFu + ((u >> 16) & 1u);
  return (u16)(r >> 16);
}
__device__ __forceinline__ float blo(u32 u){ return __uint_as_float(u << 16); }
__device__ __forceinline__ float bhi(u32 u){ return __uint_as_float(u & 0xFFFF0000u); }
__device__ __forceinline__ u32 pk2(float a, float b){ return (u32)f2b(a) | ((u32)f2b(b) << 16); }

// async global->LDS, 16B/lane; dest = wave-uniform base + lane*16
__device__ __forceinline__ void gl16(const void* g, void* l){
  __builtin_amdgcn_global_load_lds((const __attribute__((address_space(1))) void*)g,
                                   (__attribute__((address_space(3))) void*)l, 16, 0, 0);
}
__device__ __forceinline__ float gelu_f(float x){ return 0.5f*x*(1.f+erff(x*0.70710678118654752f)); }

// ---------------------------------------------------------------------------
// pack kernel:
//  - weight transpose+bf16 (Wt[N][K]) for glb_wk / glb_wq / glb_fc / w1 / w2
//  - conv2-folded transpose of glb_wq -> wq2_t  (Q = X1 @ Wq2)
//  - inp -> bf16
//  - Wc fold (f32): Wc_t[n][e] = sum_m (conv1-fold ctx_wq)[e][m] * ctx_fc[m][n]
// ---------------------------------------------------------------------------
__device__ inline void tr_tile(const float* __restrict__ src, u16* __restrict__ dst,
                               int K, int N, int ntk, int tb, float* Tsh){
  int tk = tb % ntk, tn = tb / ntk;
  int t = threadIdx.x;
  int r = t >> 2, q = t & 3;
  const float* s = src + (size_t)(tk*64 + r)*N + tn*64 + q*16;
  #pragma unroll
  for (int u2 = 0; u2 < 4; u2++){
    float4 v = *(const float4*)(s + u2*4);
    Tsh[r*65 + q*16 + u2*4 + 0] = v.x;
    Tsh[r*65 + q*16 + u2*4 + 1] = v.y;
    Tsh[r*65 + q*16 + u2*4 + 2] = v.z;
    Tsh[r*65 + q*16 + u2*4 + 3] = v.w;
  }
  __syncthreads();
  int n = t >> 2, kq = t & 3;
  u16* d = dst + (size_t)(tn*64 + n)*K + tk*64 + kq*16;
  u32 u[8];
  #pragma unroll
  for (int j = 0; j < 8; j++){
    u32 lo = f2b(Tsh[(kq*16 + 2*j    )*65 + n]);
    u32 hi = f2b(Tsh[(kq*16 + 2*j + 1)*65 + n]);
    u[j] = lo | (hi << 16);
  }
  ((uint4*)d)[0] = make_uint4(u[0],u[1],u[2],u[3]);
  ((uint4*)d)[1] = make_uint4(u[4],u[5],u[6],u[7]);
}

// transpose with conv fold along source-row axis: W2[e][n] = c0*src[e+1][n] +
// c1*src[e][n] + c2*src[e-1][n], zero-padded. Tsh rows 0..65 = src rows
// tk*64-1 .. tk*64+64.
__device__ inline void tr_tile_conv(const float* __restrict__ src, u16* __restrict__ dst,
                                    int tb, const float* __restrict__ cw, float* Tsh){
  int tk = tb & 7, tn = tb >> 3;   // 512x512
  int t = threadIdx.x;
  int r = t >> 2, q = t & 3;
  const float* s = src + (size_t)(tk*64 + r)*512 + tn*64 + q*16;
  #pragma unroll
  for (int u2 = 0; u2 < 4; u2++){
    float4 v = *(const float4*)(s + u2*4);
    Tsh[(r+1)*65 + q*16 + u2*4 + 0] = v.x;
    Tsh[(r+1)*65 + q*16 + u2*4 + 1] = v.y;
    Tsh[(r+1)*65 + q*16 + u2*4 + 2] = v.z;
    Tsh[(r+1)*65 + q*16 + u2*4 + 3] = v.w;
  }
  if (t < 64){
    Tsh[t] = (tk > 0) ? src[(size_t)(tk*64 - 1)*512 + tn*64 + t] : 0.f;
  } else if (t < 128){
    int tt = t - 64;
    Tsh[65*65 + tt] = (tk < 7) ? src[(size_t)(tk*64 + 64)*512 + tn*64 + tt] : 0.f;
  }
  __syncthreads();
  float c0 = cw[0], c1 = cw[1], c2 = cw[2];
  int n = t >> 2, kq = t & 3;
  u16* d = dst + (size_t)(tn*64 + n)*512 + tk*64 + kq*16;
  u32 u[8];
  #pragma unroll
  for (int j = 0; j < 8; j++){
    float lo = c0*Tsh[(kq*16 + 2*j + 2)*65 + n] + c1*Tsh[(kq*16 + 2*j + 1)*65 + n]
             + c2*Tsh[(kq*16 + 2*j    )*65 + n];
    float hi = c0*Tsh[(kq*16 + 2*j + 3)*65 + n] + c1*Tsh[(kq*16 + 2*j + 2)*65 + n]
             + c2*Tsh[(kq*16 + 2*j + 1)*65 + n];
    u[j] = pk2(lo, hi);
  }
  ((uint4*)d)[0] = make_uint4(u[0],u[1],u[2],u[3]);
  ((uint4*)d)[1] = make_uint4(u[4],u[5],u[6],u[7]);
}

__global__ __launch_bounds__(256) void pack_k(
    const float* __restrict__ inp,
    const float* __restrict__ ctx_wq, const float* __restrict__ ctx_fc,
    const float* __restrict__ glb_wq, const float* __restrict__ glb_wk,
    const float* __restrict__ glb_fc,
    const float* __restrict__ w1, const float* __restrict__ w2,
    const float* __restrict__ c1w, const float* __restrict__ c2w,
    u16* wk_t, u16* wq_t, u16* wq2_t, u16* gfc_t, u16* Wc_t,
    u16* w1_t, u16* w2_t, u16* inp_bf)
{
  __shared__ float Tsh[66*65];
  int bx = blockIdx.x, t = threadIdx.x;
  if (bx < 192){
    int m = bx >> 6, tb = bx & 63;
    const float* s; u16* d;
    if      (m == 0){ s = glb_wk; d = wk_t; }
    else if (m == 1){ s = glb_wq; d = wq_t; }
    else            { s = glb_fc; d = gfc_t; }
    tr_tile(s, d, 512, 512, 8, tb, Tsh);
  } else if (bx < 256){
    tr_tile_conv(glb_wq, wq2_t, bx - 192, c2w, Tsh);
  } else if (bx < 512){
    tr_tile(w1, w1_t, 512, 2048, 8, bx - 256, Tsh);
  } else if (bx < 768){
    tr_tile(w2, w2_t, 2048, 512, 32, bx - 512, Tsh);
  } else if (bx < 1792){
    size_t i0 = (size_t)(bx - 768)*2048 + (size_t)t*8;
    float4 v0 = *(const float4*)(inp + i0);
    float4 v1 = *(const float4*)(inp + i0 + 4);
    uint4 o;
    o.x = pk2(v0.x, v0.y); o.y = pk2(v0.z, v0.w);
    o.z = pk2(v1.x, v1.y); o.w = pk2(v1.z, v1.w);
    *(uint4*)(inp_bf + i0) = o;
  } else {
    // Wc fold: 64 blocks, 64x64 output tile each, K=512 f32.
    // Wc_t[n][e] = sum_m Wt1[e][m] * ctx_fc[m][n],
    // Wt1[e][m] = c0*ctx_wq[e+1][m] + c1*ctx_wq[e][m] + c2*ctx_wq[e-1][m]
    float* Fsh = Tsh;           // [16][65]
    float* Qsh = Tsh + 2048;    // [64][17]
    int tb = bx - 1792;
    int n0 = (tb >> 3)*64, e0 = (tb & 7)*64;
    float c0 = c1w[0], c1 = c1w[1], c2 = c1w[2];
    int tr = t >> 4, tc = t & 15;
    float acc[4][4] = {};
    for (int mc = 0; mc < 32; mc++){
      int m0 = mc*16;
      __syncthreads();
      #pragma unroll
      for (int i = 0; i < 4; i++){
        int idx = t + i*256;
        int fr = idx >> 6, fc = idx & 63;
        Fsh[fr*65 + fc] = ctx_fc[(size_t)(m0 + fr)*512 + n0 + fc];
        int qe = idx >> 4, qm = idx & 15;
        int ge = e0 + qe;
        float a  = ctx_wq[(size_t)ge*512 + m0 + qm];
        float bm = (ge > 0)   ? ctx_wq[(size_t)(ge-1)*512 + m0 + qm] : 0.f;
        float cp = (ge < 511) ? ctx_wq[(size_t)(ge+1)*512 + m0 + qm] : 0.f;
        Qsh[qe*17 + qm] = c0*cp + c1*a + c2*bm;
      }
      __syncthreads();
      #pragma unroll
      for (int m = 0; m < 16; m++){
        float fv[4], qv[4];
        #pragma unroll
        for (int j = 0; j < 4; j++) fv[j] = Fsh[m*65 + tc*4 + j];
        #pragma unroll
        for (int i = 0; i < 4; i++) qv[i] = Qsh[(tr*4 + i)*17 + m];
        #pragma unroll
        for (int i = 0; i < 4; i++)
          #pragma unroll
          for (int j = 0; j < 4; j++)
            acc[i][j] += qv[i]*fv[j];
      }
    }
    #pragma unroll
    for (int i = 0; i < 4; i++)
      #pragma unroll
      for (int j = 0; j < 4; j++)
        Wc_t[(size_t)(n0 + tc*4 + j)*512 + e0 + tr*4 + i] = f2b(acc[i][j]);
  }
}

// ---------------------------------------------------------------------------
// gemm128: C = A[M][lda]*Bt[N][ldb]^T, tile 128x128, BK=64, 4 waves,
// wave tile 64x64 = acc[4][4]. 2-buffer LDS (64KB), prefetch-before-compute,
// one __syncthreads per K-step (R7 proven). XOR swizzle (rule #21).
// outm: 0=f32, 1=bf16(+bias/act), 2=Vt-transpose.
// ---------------------------------------------------------------------------
template<int BIAS,int ACT>
__device__ __forceinline__ void gemm128_core(const u16* __restrict__ A,
    const u16* __restrict__ Bt, const float* __restrict__ bias,
    void* __restrict__ Cb, int N, int K, int lda, int ldb, int outm,
    u16* sm, int row0, int col0)
{
  const int tid = threadIdx.x;
  const int w = tid >> 6, l = tid & 63;
  const int wr = w >> 1, wc = w & 1;
  const int l15 = l & 15, lk = (l >> 4)*16;
  const int srow = tid >> 3;
  const int scol = (((tid & 7)*16) ^ ((srow & 7) << 4)) >> 1;
  const u16* pa = A  + (size_t)(row0 + srow)*lda + scol;
  const u16* pb = Bt + (size_t)(col0 + srow)*ldb + scol;
  char* lA = (char*)sm + (tid & ~63)*16;            // A bufs at 0, 16384
  char* lB = (char*)sm + 32768 + (tid & ~63)*16;    // B bufs at 32768, 49152

  f32x4 acc[4][4] = {};
  const int nt = K >> 6;

  auto STAGE = [&](int buf, int kt){
    char* a = lA + buf*16384;
    char* b = lB + buf*16384;
    #pragma unroll
    for (int i = 0; i < 4; i++){
      gl16(pa + kt + (size_t)(i*32)*lda, a + i*4096);
      gl16(pb + kt + (size_t)(i*32)*ldb, b + i*4096);
    }
  };

  STAGE(0, 0);
  __syncthreads();
  for (int t = 0; t < nt; ++t){
    if (t + 1 < nt) STAGE((t+1) & 1, (t+1)*64);
    const char* bA = (const char*)sm + (t&1)*16384;
    const char* bB = (const char*)sm + 32768 + (t&1)*16384;
    #pragma unroll
    for (int ks = 0; ks < 2; ks++){
      bf16x8 af[4], bv[4];
      #pragma unroll
      for (int m = 0; m < 4; m++){
        int r = wr*64 + m*16 + l15;
        af[m] = *(const bf16x8*)(bA + r*128 + ((ks*64 + lk) ^ ((r & 7) << 4)));
      }
      #pragma unroll
      for (int n = 0; n < 4; n++){
        int r = wc*64 + n*16 + l15;
        bv[n] = *(const bf16x8*)(bB + r*128 + ((ks*64 + lk) ^ ((r & 7) << 4)));
      }
      #pragma unroll
      for (int m = 0; m < 4; m++)
        #pragma unroll
        for (int n = 0; n < 4; n++)
          acc[m][n] = __builtin_amdgcn_mfma_f32_16x16x32_bf16(af[m], bv[n], acc[m][n], 0, 0, 0);
    }
    __syncthreads();
  }

  #pragma unroll
  for (int m = 0; m < 4; m++){
    #pragma unroll
    for (int n = 0; n < 4; n++){
      int col = col0 + wc*64 + n*16 + l15;
      int rowb = row0 + wr*64 + m*16 + (l >> 4)*4;
      if (outm == 2){
        uint2 o;
        o.x = pk2(acc[m][n][0], acc[m][n][1]);
        o.y = pk2(acc[m][n][2], acc[m][n][3]);
        *(uint2*)((u16*)Cb + (size_t)(rowb >> 8)*131072 + (size_t)col*256 + (rowb & 255)) = o;
      } else if (outm == 0){
        #pragma unroll
        for (int rr = 0; rr < 4; rr++)
          ((float*)Cb)[(size_t)(rowb + rr)*N + col] = acc[m][n][rr];
      } else {
        #pragma unroll
        for (int rr = 0; rr < 4; rr++){
          float v = acc[m][n][rr];
          if (BIAS) v += bias[col];
          if (ACT)  v = gelu_f(v);
          ((u16*)Cb)[(size_t)(rowb + rr)*N + col] = f2b(v);
        }
      }
    }
  }
}

template<int BIAS,int ACT>
__global__ __launch_bounds__(256) void gemm128_k(const u16* __restrict__ A,
                                                 const u16* __restrict__ Bt,
                                                 const float* __restrict__ bias,
                                                 void* __restrict__ Cb, int N, int K)
{
  __shared__ u16 sm[32768];  // 64KB
  gemm128_core<BIAS,ACT>(A, Bt, bias, Cb, N, K, K, K, 1, sm,
                         blockIdx.y*128, blockIdx.x*128);
}

// merged Kg / Vt / ctx — all share A = inp_bf (L2-friendly), z selects B/C
__global__ __launch_bounds__(256) void gemm3_k(
    const u16* __restrict__ A,
    const u16* __restrict__ B0, u16* __restrict__ C0,
    const u16* __restrict__ B1, u16* __restrict__ C1,
    const u16* __restrict__ B2, u16* __restrict__ C2)
{
  __shared__ u16 sm[32768];
  const u16 *Bt; u16* Cb; int outm = 1;
  if (blockIdx.z == 0){ Bt = B0; Cb = C0; }
  else if (blockIdx.z == 1){ Bt = B1; Cb = C1; outm = 2; }
  else { Bt = B2; Cb = C2; }
  gemm128_core<0,0>(A, Bt, nullptr, Cb, 512, 512, 512, 512, outm, sm,
                    blockIdx.y*128, blockIdx.x*128);
}

// split-K w2: K=2048 split in 2, f32 partials P[z][4096][512]  (R7 proven)
__global__ __launch_bounds__(256) void gemm_w2sk(const u16* __restrict__ G,
                                                 const u16* __restrict__ w2t,
                                                 float* __restrict__ P)
{
  __shared__ u16 sm[32768];
  const int z = blockIdx.z;
  gemm128_core<0,0>(G + z*1024, w2t + z*1024, nullptr,
                    (void*)(P + (size_t)z*NT*512), 512, 1024, 2048, 2048, 0,
                    sm, blockIdx.y*128, blockIdx.x*128);
}

// ---------------------------------------------------------------------------
// gemm64: 64x64 tile, acc[2][2], 2-buffer (32KB). bf16 out. (R7 proven)
// ---------------------------------------------------------------------------
__global__ __launch_bounds__(256) void gemm64_k(const u16* __restrict__ A,
                                                const u16* __restrict__ Bt,
                                                u16* __restrict__ Cb, int N, int K)
{
  __shared__ u16 sm[16384];
  const int tid = threadIdx.x;
  const int w = tid >> 6, l = tid & 63;
  const int wr = w >> 1, wc = w & 1;
  const int l15 = l & 15, lk = (l >> 4)*16;
  const int row0 = blockIdx.y*64, col0 = blockIdx.x*64;
  const int srow = tid >> 3;
  const int scol = (((tid & 7)*16) ^ ((srow & 7) << 4)) >> 1;
  const u16* pa = A  + (size_t)(row0 + srow)*K + scol;
  const u16* pb = Bt + (size_t)(col0 + srow)*K + scol;
  char* lA = (char*)sm + (tid & ~63)*16;

  f32x4 acc[2][2] = {};
  const int nt = K >> 6;
  auto STAGE = [&](int buf, int kt){
    char* a = lA + buf*8192;
    char* b = lA + 16384 + buf*8192;
    gl16(pa + kt,                a);
    gl16(pa + kt + (size_t)32*K, a + 4096);
    gl16(pb + kt,                b);
    gl16(pb + kt + (size_t)32*K, b + 4096);
  };
  STAGE(0, 0);
  __syncthreads();
  for (int t = 0; t < nt; ++t){
    if (t + 1 < nt) STAGE((t+1) & 1, (t+1)*64);
    const char* bA = (const char*)sm + (t&1)*8192;
    const char* bB = (const char*)sm + 16384 + (t&1)*8192;
    #pragma unroll
    for (int ks = 0; ks < 2; ks++){
      bf16x8 af[2], bv[2];
      #pragma unroll
      for (int m = 0; m < 2; m++){
        int r = wr*32 + m*16 + l15;
        af[m] = *(const bf16x8*)(bA + r*128 + ((ks*64 + lk) ^ ((r & 7) << 4)));
      }
      #pragma unroll
      for (int n = 0; n < 2; n++){
        int r = wc*32 + n*16 + l15;
        bv[n] = *(const bf16x8*)(bB + r*128 + ((ks*64 + lk) ^ ((r & 7) << 4)));
      }
      #pragma unroll
      for (int m = 0; m < 2; m++)
        #pragma unroll
        for (int n = 0; n < 2; n++)
          acc[m][n] = __builtin_amdgcn_mfma_f32_16x16x32_bf16(af[m], bv[n], acc[m][n], 0, 0, 0);
    }
    __syncthreads();
  }
  #pragma unroll
  for (int m = 0; m < 2; m++){
    #pragma unroll
    for (int n = 0; n < 2; n++){
      int col = col0 + wc*32 + n*16 + l15;
      int rowb = row0 + wr*32 + m*16 + (l >> 4)*4;
      #pragma unroll
      for (int rr = 0; rr < 4; rr++)
        Cb[(size_t)(rowb + rr)*N + col] = f2b(acc[m][n][rr]);
    }
  }
}

// ---------------------------------------------------------------------------
// qattn: fused Q-GEMM (64x64 tile, B = conv2-folded Wq2) + MFMA flash attn.
// grid (8 heads, 64 token-tiles). LDS 80KB (R7 proven):
//  [0,32K) gemm staging -> reused as K [256 key][64 d]
//  [32K,40K) Q tile [64 q][64 d]   [40K,72K) V [64 d][256 t]   [72K,80K) P
// ---------------------------------------------------------------------------
__global__ __launch_bounds__(256) void qattn_k(const u16* __restrict__ X1,
                                               const u16* __restrict__ Wq2,
                                               const u16* __restrict__ Kg,
                                               const u16* __restrict__ Vt,
                                               u16* __restrict__ O)
{
  __shared__ u16 sm[40960];   // 80KB
  const int h = blockIdx.x, ty = blockIdx.y;
  const int b = ty >> 2, bh = b*8 + h;
  const int tid = threadIdx.x;
  const int w = tid >> 6, l = tid & 63;
  const int l15 = l & 15, lg = l >> 4;
  const int wr = w >> 1, wc = w & 1;
  const int lk = lg*16;

  // V prefetch (8 gl16/thread) into [40K,72K): rows = d (512B), swizzled
  {
    const int vrow = tid >> 5;
    const int vcb  = (tid*16) & 511;
    const int scolV = (vcb ^ ((vrow & 7) << 4)) >> 1;
    const u16* pv = Vt + (size_t)bh*16384 + (size_t)vrow*256 + scolV;
    char* lV = (char*)sm + 40960 + (tid & ~63)*16;
    #pragma unroll
    for (int c = 0; c < 8; c++)
      gl16(pv + (size_t)(c*8)*256, lV + c*4096);
  }

  // ---- Q GEMM: Q = X1[ty*64..+64] @ Wq2[h*64..+64]^T, K=512 ----
  const int srow = tid >> 3;
  const int scol = (((tid & 7)*16) ^ ((srow & 7) << 4)) >> 1;
  const u16* pa = X1 + (size_t)(ty*64 + srow)*512 + scol;
  const u16* pb = Wq2 + (size_t)(h*64 + srow)*512 + scol;
  char* lS = (char*)sm + (tid & ~63)*16;

  auto QSTG = [&](int buf, int kt){
    char* a = lS + buf*8192;
    char* bq = lS + 16384 + buf*8192;
    gl16(pa + kt,              a);
    gl16(pa + kt + 32*512,     a + 4096);
    gl16(pb + kt,              bq);
    gl16(pb + kt + 32*512,     bq + 4096);
  };

  f32x4 qacc[2][2] = {};
  QSTG(0, 0);
  __syncthreads();
  for (int t = 0; t < 8; ++t){
    if (t < 7) QSTG((t+1) & 1, (t+1)*64);
    const char* bA = (const char*)sm + (t&1)*8192;
    const char* bB = (const char*)sm + 16384 + (t&1)*8192;
    #pragma unroll
    for (int ks = 0; ks < 2; ks++){
      bf16x8 af[2], bv[2];
      #pragma unroll
      for (int m = 0; m < 2; m++){
        int r = wr*32 + m*16 + l15;
        af[m] = *(const bf16x8*)(bA + r*128 + ((ks*64 + lk) ^ ((r & 7) << 4)));
      }
      #pragma unroll
      for (int n = 0; n < 2; n++){
        int r = wc*32 + n*16 + l15;
        bv[n] = *(const bf16x8*)(bB + r*128 + ((ks*64 + lk) ^ ((r & 7) << 4)));
      }
      #pragma unroll
      for (int m = 0; m < 2; m++)
        #pragma unroll
        for (int n = 0; n < 2; n++)
          qacc[m][n] = __builtin_amdgcn_mfma_f32_16x16x32_bf16(af[m], bv[n], qacc[m][n], 0, 0, 0);
    }
    __syncthreads();
  }

  // stage K into retired staging region [0,32K)
  {
    const u16* pk = Kg + (size_t)(b*256 + srow)*512 + h*64 + scol;
    char* lK = (char*)sm + (tid & ~63)*16;
    #pragma unroll
    for (int c = 0; c < 8; c++)
      gl16(pk + (size_t)(c*32)*512, lK + c*4096);
  }
  // write Q tile (bf16, swizzled) to [32K,40K)
  #pragma unroll
  for (int m = 0; m < 2; m++)
    #pragma unroll
    for (int n = 0; n < 2; n++)
      #pragma unroll
      for (int rr = 0; rr < 4; rr++){
        int row = wr*32 + m*16 + (l >> 4)*4 + rr;
        int col = wc*32 + n*16 + l15;
        *(u16*)((char*)sm + 32768 + row*128 + ((col*2) ^ ((row & 7) << 4))) = f2b(qacc[m][n][rr]);
      }
  __syncthreads();   // Q visible; implicit vmcnt(0) also lands K and V

  // ---- attention ----
  const int qt0 = b*256 + (ty & 3)*64 + w*16;
  bf16x8 aq[2];
  #pragma unroll
  for (int ks = 0; ks < 2; ks++){
    int qr = w*16 + l15;
    aq[ks] = *(const bf16x8*)((char*)sm + 32768 + qr*128 + ((ks*64 + lk) ^ ((qr & 7) << 4)));
  }
  char* Pw = (char*)sm + 73728 + w*2048;

  f32x4 oacc[4] = {};
  float rsum[4] = {0.f, 0.f, 0.f, 0.f};

  #pragma unroll
  for (int c = 0; c < 4; c++){
    f32x4 sacc[4] = {};
    #pragma unroll
    for (int n = 0; n < 4; n++){
      int r = c*64 + n*16 + l15;
      #pragma unroll
      for (int ks = 0; ks < 2; ks++){
        bf16x8 bk = *(const bf16x8*)((const char*)sm + r*128 + ((ks*64 + lk) ^ ((r & 7) << 4)));
        sacc[n] = __builtin_amdgcn_mfma_f32_16x16x32_bf16(aq[ks], bk, sacc[n], 0, 0, 0);
      }
    }
    #pragma unroll
    for (int n = 0; n < 4; n++){
      #pragma unroll
      for (int rr = 0; rr < 4; rr++){
        float p = __expf(sacc[n][rr]*0.125f);
        rsum[rr] += p;
        int q = lg*4 + rr, key = n*16 + l15;
        *(u16*)(Pw + ((q*128 + key*2) ^ ((q & 7) << 4))) = f2b(p);
      }
    }
    bf16x8 ap[2];
    #pragma unroll
    for (int ks2 = 0; ks2 < 2; ks2++)
      ap[ks2] = *(const bf16x8*)(Pw + l15*128 + ((ks2*64 + lk) ^ ((l15 & 7) << 4)));
    #pragma unroll
    for (int n = 0; n < 4; n++){
      int r = n*16 + l15;   // d index
      #pragma unroll
      for (int ks2 = 0; ks2 < 2; ks2++){
        bf16x8 bvv = *(const bf16x8*)((const char*)sm + 40960 + r*512 +
                                      ((c*128 + ks2*64 + lk) ^ ((r & 7) << 4)));
        oacc[n] = __builtin_amdgcn_mfma_f32_16x16x32_bf16(ap[ks2], bvv, oacc[n], 0, 0, 0);
      }
    }
  }

  #pragma unroll
  for (int m = 1; m < 16; m <<= 1){
    #pragma unroll
    for (int rr = 0; rr < 4; rr++) rsum[rr] += __shfl_xor(rsum[rr], m);
  }
  #pragma unroll
  for (int n = 0; n < 4; n++){
    int d = h*64 + n*16 + l15;
    #pragma unroll
    for (int rr = 0; rr < 4; rr++){
      int t = qt0 + lg*4 + rr;
      O[(size_t)t*ND + d] = f2b(oacc[n][rr]/rsum[rr]);
    }
  }
}

// ---------------------------------------------------------------------------
// fused residual-add + LayerNorm (D=512).
// MODE0: a=bf16, b=f32 -> bf.   MODE1: a=bf16, b=bf16 -> bf + hn rows (f32 a).
// MODE3: a=P0 f32, a2=P1 f32, bias2; b=bf16 -> f32 (split-K reduce fused).
// ---------------------------------------------------------------------------
template<int MODE>
__global__ __launch_bounds__(256) void ln_k(const void* __restrict__ aptr,
                                            const void* __restrict__ bptr,
                                            const float* __restrict__ g,
                                            const float* __restrict__ be,
                                            const float* __restrict__ a2,
                                            const float* __restrict__ bias2,
                                            u16* __restrict__ obf,
                                            float* __restrict__ of32,
                                            float* __restrict__ hnout)
{
  __shared__ float red[10];
  const int r0 = blockIdx.x, tid = threadIdx.x;
  const size_t base = (size_t)r0*ND;
  const int d = tid*2;
  float v0, v1;
  if (MODE == 3){
    float2 p0 = *(const float2*)((const float*)aptr + base + d);
    float2 p1 = *(const float2*)(a2 + base + d);
    u32 bv = *(const u32*)((const u16*)bptr + base + d);
    v0 = p0.x + p1.x + bias2[d]   + blo(bv);
    v1 = p0.y + p1.y + bias2[d+1] + bhi(bv);
  } else {
    u32 av = *(const u32*)((const u16*)aptr + base + d);
    v0 = blo(av); v1 = bhi(av);
    if (MODE == 1 && (r0 & 255) == 255){
      hnout[(size_t)(r0 >> 8)*512 + d]     = v0;
      hnout[(size_t)(r0 >> 8)*512 + d + 1] = v1;
    }
    if (MODE == 0){
      float2 bv = *(const float2*)((const float*)bptr + base + d);
      v0 += bv.x; v1 += bv.y;
    } else {
      u32 bv = *(const u32*)((const u16*)bptr + base + d);
      v0 += blo(bv); v1 += bhi(bv);
    }
  }
  float s = v0+v1, ss = v0*v0+v1*v1;
  #pragma unroll
  for (int m = 1; m < 64; m <<= 1){ s += __shfl_xor(s, m); ss += __shfl_xor(ss, m); }
  int wv = tid >> 6;
  if ((tid & 63) == 0){ red[wv] = s; red[4+wv] = ss; }
  __syncthreads();
  if (tid == 0){
    float S = red[0]+red[1]+red[2]+red[3];
    float SS = red[4]+red[5]+red[6]+red[7];
    float mu = S*(1.f/ND);
    float var = SS*(1.f/ND) - mu*mu;
    red[8] = mu; red[9] = rsqrtf(var + 1e-5f);
  }
  __syncthreads();
  float mu = red[8], rsd = red[9];
  float o0 = (v0-mu)*rsd*g[d]   + be[d];
  float o1 = (v1-mu)*rsd*g[d+1] + be[d+1];
  if (MODE == 3){
    *(float2*)(of32 + base + d) = make_float2(o0, o1);
  } else {
    *(u32*)(obf + base + d) = pk2(o0, o1);
  }
}

// ---------------------------------------------------------------------------
extern "C" void kernel_launch(void* const* d_in, const int* in_sizes, int n_in,
                              void* d_out, int out_size, void* d_ws, size_t ws_size,
                              hipStream_t stream) {
  const float* inp     = (const float*)d_in[0];
  const float* conv1_w = (const float*)d_in[1];
  const float* conv2_w = (const float*)d_in[2];
  const float* ctx_wq  = (const float*)d_in[3];
  // d_in[4] = ctx_wk : provably unused (softmax over singleton key axis == 1)
  const float* ctx_fc  = (const float*)d_in[5];
  const float* glb_wq  = (const float*)d_in[6];
  const float* glb_wk  = (const float*)d_in[7];
  const float* glb_fc  = (const float*)d_in[8];
  const float* ln1_g = (const float*)d_in[9],  *ln1_b = (const float*)d_in[10];
  const float* ln2_g = (const float*)d_in[11], *ln2_b = (const float*)d_in[12];
  const float* ln3_g = (const float*)d_in[13], *ln3_b = (const float*)d_in[14];
  const float* mlp_w1 = (const float*)d_in[15], *mlp_b1 = (const float*)d_in[16];
  const float* mlp_w2 = (const float*)d_in[17], *mlp_b2 = (const float*)d_in[18];
  float* out = (float*)d_out;
  float* hn  = out + (size_t)NT*ND;

  u16* wk_t   = (u16*)d_ws;
  u16* wq_t   = wk_t   + 262144;
  u16* wq2_t  = wq_t   + 262144;     // conv2-folded glb_wq (for Q)
  u16* gfc_t  = wq2_t  + 262144;
  u16* Wc_t   = gfc_t  + 262144;     // conv1-folded ctx_wq @ ctx_fc, [n][k]
  u16* w1_t   = Wc_t   + 262144;     // 2048x512
  u16* w2_t   = w1_t   + 1048576;    // 512x2048
  u16* inp_bf = w2_t   + 1048576;
  u16* Abf    = inp_bf + 2097152;    // O
  u16* Cbf    = Abf    + 2097152;    // ctx -> HH
  u16* Kg     = Cbf    + 2097152;
  u16* Vt     = Kg     + 2097152;    // [b][h*64+d][t&255]
  u16* X1bf   = Vt     + 2097152;
  u16* X3bf   = X1bf   + 2097152;
  u16* Gbf    = X3bf   + 2097152;    // 4096x2048
  float* Pf   = (float*)(Gbf + 8388608);  // 2 x 4096 x 512 f32 split-K partials

  // pack: weight trs + conv2-folded wq2 + inp->bf16 + Wc fold (conv1-folded)
  pack_k<<<1856, 256, 0, stream>>>(inp, ctx_wq, ctx_fc, glb_wq, glb_wk, glb_fc,
                                   mlp_w1, mlp_w2, conv1_w, conv2_w,
                                   wk_t, wq_t, wq2_t, gfc_t, Wc_t, w1_t, w2_t,
                                   inp_bf);
  // Kg, Vt, ctx in one dispatch; all A = inp_bf (L2-shared)
  gemm3_k<<<dim3(4,32,3),256,0,stream>>>(inp_bf, wk_t, Kg, wq_t, Vt, Wc_t, Cbf);
  // LN1: X1 = LN(ctx + inp)
  ln_k<0><<<NT,256,0,stream>>>(Cbf, inp, ln1_g, ln1_b, nullptr, nullptr,
                               X1bf, nullptr, nullptr);
  // fused Q-gemm (X1 @ Wq2) + attention -> O (Abf)
  qattn_k<<<dim3(8,64),256,0,stream>>>(X1bf, wq2_t, Kg, Vt, Abf);
  // HH = O @ glb_fc
  gemm64_k<<<dim3(8,64),256,0,stream>>>(Abf, gfc_t, Cbf, 512, 512);
  // LN2 (+X1) -> X3bf, fused hn extraction
  ln_k<1><<<NT,256,0,stream>>>(Cbf, X1bf, ln2_g, ln2_b, nullptr, nullptr,
                               X3bf, nullptr, hn);
  // MLP: w1 128x128 (512 blocks); w2 split-K2 f32 partials (256 blocks)
  gemm128_k<1,1><<<dim3(16,32),256,0,stream>>>(X3bf, w1_t, mlp_b1, Gbf, 2048, 512);
  gemm_w2sk<<<dim3(4,32,2),256,0,stream>>>(Gbf, w2_t, Pf);
  // LN3: out = LN(P0+P1+b2 + X3)
  ln_k<3><<<NT,256,0,stream>>>(Pf, X3bf, ln3_g, ln3_b, Pf + (size_t)NT*512,
                               mlp_b2, nullptr, out, nullptr);
}

// Round 12
// 101.237 us; speedup vs baseline: 1.7010x; 1.7010x over previous
//
#include <hip/hip_runtime.h>
#include <math.h>

#define NBS 16
#define NL 256
#define ND 512
#define NH 8
#define NDFF 2048
#define NT (NBS*NL)   // 4096 tokens

typedef unsigned short u16;
typedef unsigned int   u32;
typedef __attribute__((ext_vector_type(8))) short bf16x8;  // 8 bf16 = 4 VGPRs
typedef __attribute__((ext_vector_type(4))) float f32x4;

__device__ __forceinline__ u16 f2b(float f){
  u32 u = __float_as_uint(f);
  u32 r = u + 0x7FFFu + ((u >> 16) & 1u);
  return (u16)(r >> 16);
}
__device__ __forceinline__ float blo(u32 u){ return __uint_as_float(u << 16); }
__device__ __forceinline__ float bhi(u32 u){ return __uint_as_float(u & 0xFFFF0000u); }
__device__ __forceinline__ u32 pk2(float a, float b){ return (u32)f2b(a) | ((u32)f2b(b) << 16); }

// async global->LDS, 16B/lane; dest = wave-uniform base + lane*16
__device__ __forceinline__ void gl16(const void* g, void* l){
  __builtin_amdgcn_global_load_lds((const __attribute__((address_space(1))) void*)g,
                                   (__attribute__((address_space(3))) void*)l, 16, 0, 0);
}
__device__ __forceinline__ float gelu_f(float x){ return 0.5f*x*(1.f+erff(x*0.70710678118654752f)); }

// ---------------------------------------------------------------------------
// pack kernel:
//  - weight transpose+bf16 (Wt[N][K]) for glb_wk / glb_wq / glb_fc / ctx_fc / w1 / w2
//  - conv2-folded transpose of glb_wq -> wq2_t  (Q = X1 @ Wq2)
//  - conv1-folded ELEMENTWISE copy of ctx_wq -> cwq1 (row-major [e][m], bf16)
//  - inp -> bf16
// (Wc fold product itself is a separate MFMA gemm64_k dispatch.)
// ---------------------------------------------------------------------------
__device__ inline void tr_tile(const float* __restrict__ src, u16* __restrict__ dst,
                               int K, int N, int ntk, int tb, float* Tsh){
  int tk = tb % ntk, tn = tb / ntk;
  int t = threadIdx.x;
  int r = t >> 2, q = t & 3;
  const float* s = src + (size_t)(tk*64 + r)*N + tn*64 + q*16;
  #pragma unroll
  for (int u2 = 0; u2 < 4; u2++){
    float4 v = *(const float4*)(s + u2*4);
    Tsh[r*65 + q*16 + u2*4 + 0] = v.x;
    Tsh[r*65 + q*16 + u2*4 + 1] = v.y;
    Tsh[r*65 + q*16 + u2*4 + 2] = v.z;
    Tsh[r*65 + q*16 + u2*4 + 3] = v.w;
  }
  __syncthreads();
  int n = t >> 2, kq = t & 3;
  u16* d = dst + (size_t)(tn*64 + n)*K + tk*64 + kq*16;
  u32 u[8];
  #pragma unroll
  for (int j = 0; j < 8; j++){
    u32 lo = f2b(Tsh[(kq*16 + 2*j    )*65 + n]);
    u32 hi = f2b(Tsh[(kq*16 + 2*j + 1)*65 + n]);
    u[j] = lo | (hi << 16);
  }
  ((uint4*)d)[0] = make_uint4(u[0],u[1],u[2],u[3]);
  ((uint4*)d)[1] = make_uint4(u[4],u[5],u[6],u[7]);
}

// transpose with conv fold along source-row axis: W2[e][n] = c0*src[e+1][n] +
// c1*src[e][n] + c2*src[e-1][n], zero-padded. (verified correct in R11)
__device__ inline void tr_tile_conv(const float* __restrict__ src, u16* __restrict__ dst,
                                    int tb, const float* __restrict__ cw, float* Tsh){
  int tk = tb & 7, tn = tb >> 3;   // 512x512
  int t = threadIdx.x;
  int r = t >> 2, q = t & 3;
  const float* s = src + (size_t)(tk*64 + r)*512 + tn*64 + q*16;
  #pragma unroll
  for (int u2 = 0; u2 < 4; u2++){
    float4 v = *(const float4*)(s + u2*4);
    Tsh[(r+1)*65 + q*16 + u2*4 + 0] = v.x;
    Tsh[(r+1)*65 + q*16 + u2*4 + 1] = v.y;
    Tsh[(r+1)*65 + q*16 + u2*4 + 2] = v.z;
    Tsh[(r+1)*65 + q*16 + u2*4 + 3] = v.w;
  }
  if (t < 64){
    Tsh[t] = (tk > 0) ? src[(size_t)(tk*64 - 1)*512 + tn*64 + t] : 0.f;
  } else if (t < 128){
    int tt = t - 64;
    Tsh[65*65 + tt] = (tk < 7) ? src[(size_t)(tk*64 + 64)*512 + tn*64 + tt] : 0.f;
  }
  __syncthreads();
  float c0 = cw[0], c1 = cw[1], c2 = cw[2];
  int n = t >> 2, kq = t & 3;
  u16* d = dst + (size_t)(tn*64 + n)*512 + tk*64 + kq*16;
  u32 u[8];
  #pragma unroll
  for (int j = 0; j < 8; j++){
    float lo = c0*Tsh[(kq*16 + 2*j + 2)*65 + n] + c1*Tsh[(kq*16 + 2*j + 1)*65 + n]
             + c2*Tsh[(kq*16 + 2*j    )*65 + n];
    float hi = c0*Tsh[(kq*16 + 2*j + 3)*65 + n] + c1*Tsh[(kq*16 + 2*j + 2)*65 + n]
             + c2*Tsh[(kq*16 + 2*j + 1)*65 + n];
    u[j] = pk2(lo, hi);
  }
  ((uint4*)d)[0] = make_uint4(u[0],u[1],u[2],u[3]);
  ((uint4*)d)[1] = make_uint4(u[4],u[5],u[6],u[7]);
}

__global__ __launch_bounds__(256) void pack_k(
    const float* __restrict__ inp,
    const float* __restrict__ ctx_wq, const float* __restrict__ ctx_fc,
    const float* __restrict__ glb_wq, const float* __restrict__ glb_wk,
    const float* __restrict__ glb_fc,
    const float* __restrict__ w1, const float* __restrict__ w2,
    const float* __restrict__ c1w, const float* __restrict__ c2w,
    u16* wk_t, u16* wq_t, u16* wq2_t, u16* gfc_t, u16* cfc_t, u16* cwq1,
    u16* w1_t, u16* w2_t, u16* inp_bf)
{
  __shared__ float Tsh[66*65];
  int bx = blockIdx.x, t = threadIdx.x;
  if (bx < 256){
    int m = bx >> 6, tb = bx & 63;
    const float* s; u16* d;
    if      (m == 0){ s = glb_wk; d = wk_t; }
    else if (m == 1){ s = glb_wq; d = wq_t; }
    else if (m == 2){ s = glb_fc; d = gfc_t; }
    else            { s = ctx_fc; d = cfc_t; }
    tr_tile(s, d, 512, 512, 8, tb, Tsh);
  } else if (bx < 320){
    tr_tile_conv(glb_wq, wq2_t, bx - 256, c2w, Tsh);
  } else if (bx < 576){
    tr_tile(w1, w1_t, 512, 2048, 8, bx - 320, Tsh);
  } else if (bx < 832){
    tr_tile(w2, w2_t, 2048, 512, 32, bx - 576, Tsh);
  } else if (bx < 1856){
    size_t i0 = (size_t)(bx - 832)*2048 + (size_t)t*8;
    float4 v0 = *(const float4*)(inp + i0);
    float4 v1 = *(const float4*)(inp + i0 + 4);
    uint4 o;
    o.x = pk2(v0.x, v0.y); o.y = pk2(v0.z, v0.w);
    o.z = pk2(v1.x, v1.y); o.w = pk2(v1.z, v1.w);
    *(uint4*)(inp_bf + i0) = o;
  } else {
    // conv1-folded elementwise copy of ctx_wq:
    // cwq1[e][m] = c0*ctx_wq[e+1][m] + c1*ctx_wq[e][m] + c2*ctx_wq[e-1][m]
    size_t i0 = (size_t)(bx - 1856)*2048 + (size_t)t*8;   // 8 elems, one row
    int e = (int)(i0 >> 9);
    float c0 = c1w[0], c1 = c1w[1], c2 = c1w[2];
    float4 a0 = *(const float4*)(ctx_wq + i0);
    float4 a1 = *(const float4*)(ctx_wq + i0 + 4);
    float4 p0 = make_float4(0,0,0,0), p1 = p0, m0 = p0, m1 = p0;
    if (e < 511){ p0 = *(const float4*)(ctx_wq + i0 + 512); p1 = *(const float4*)(ctx_wq + i0 + 516); }
    if (e > 0)  { m0 = *(const float4*)(ctx_wq + i0 - 512); m1 = *(const float4*)(ctx_wq + i0 - 508); }
    uint4 o;
    o.x = pk2(c0*p0.x + c1*a0.x + c2*m0.x, c0*p0.y + c1*a0.y + c2*m0.y);
    o.y = pk2(c0*p0.z + c1*a0.z + c2*m0.z, c0*p0.w + c1*a0.w + c2*m0.w);
    o.z = pk2(c0*p1.x + c1*a1.x + c2*m1.x, c0*p1.y + c1*a1.y + c2*m1.y);
    o.w = pk2(c0*p1.z + c1*a1.z + c2*m1.z, c0*p1.w + c1*a1.w + c2*m1.w);
    *(uint4*)(cwq1 + i0) = o;
  }
}

// ---------------------------------------------------------------------------
// gemm128: C = A[M][lda]*Bt[N][ldb]^T, tile 128x128, BK=64, 4 waves,
// wave tile 64x64 = acc[4][4]. 2-buffer LDS (64KB), prefetch-before-compute,
// one __syncthreads per K-step (R7 proven). XOR swizzle (rule #21).
// outm: 0=f32, 1=bf16(+bias/act), 2=Vt-transpose.
// ---------------------------------------------------------------------------
template<int BIAS,int ACT>
__device__ __forceinline__ void gemm128_core(const u16* __restrict__ A,
    const u16* __restrict__ Bt, const float* __restrict__ bias,
    void* __restrict__ Cb, int N, int K, int lda, int ldb, int outm,
    u16* sm, int row0, int col0)
{
  const int tid = threadIdx.x;
  const int w = tid >> 6, l = tid & 63;
  const int wr = w >> 1, wc = w & 1;
  const int l15 = l & 15, lk = (l >> 4)*16;
  const int srow = tid >> 3;
  const int scol = (((tid & 7)*16) ^ ((srow & 7) << 4)) >> 1;
  const u16* pa = A  + (size_t)(row0 + srow)*lda + scol;
  const u16* pb = Bt + (size_t)(col0 + srow)*ldb + scol;
  char* lA = (char*)sm + (tid & ~63)*16;            // A bufs at 0, 16384
  char* lB = (char*)sm + 32768 + (tid & ~63)*16;    // B bufs at 32768, 49152

  f32x4 acc[4][4] = {};
  const int nt = K >> 6;

  auto STAGE = [&](int buf, int kt){
    char* a = lA + buf*16384;
    char* b = lB + buf*16384;
    #pragma unroll
    for (int i = 0; i < 4; i++){
      gl16(pa + kt + (size_t)(i*32)*lda, a + i*4096);
      gl16(pb + kt + (size_t)(i*32)*ldb, b + i*4096);
    }
  };

  STAGE(0, 0);
  __syncthreads();
  for (int t = 0; t < nt; ++t){
    if (t + 1 < nt) STAGE((t+1) & 1, (t+1)*64);
    const char* bA = (const char*)sm + (t&1)*16384;
    const char* bB = (const char*)sm + 32768 + (t&1)*16384;
    #pragma unroll
    for (int ks = 0; ks < 2; ks++){
      bf16x8 af[4], bv[4];
      #pragma unroll
      for (int m = 0; m < 4; m++){
        int r = wr*64 + m*16 + l15;
        af[m] = *(const bf16x8*)(bA + r*128 + ((ks*64 + lk) ^ ((r & 7) << 4)));
      }
      #pragma unroll
      for (int n = 0; n < 4; n++){
        int r = wc*64 + n*16 + l15;
        bv[n] = *(const bf16x8*)(bB + r*128 + ((ks*64 + lk) ^ ((r & 7) << 4)));
      }
      #pragma unroll
      for (int m = 0; m < 4; m++)
        #pragma unroll
        for (int n = 0; n < 4; n++)
          acc[m][n] = __builtin_amdgcn_mfma_f32_16x16x32_bf16(af[m], bv[n], acc[m][n], 0, 0, 0);
    }
    __syncthreads();
  }

  #pragma unroll
  for (int m = 0; m < 4; m++){
    #pragma unroll
    for (int n = 0; n < 4; n++){
      int col = col0 + wc*64 + n*16 + l15;
      int rowb = row0 + wr*64 + m*16 + (l >> 4)*4;
      if (outm == 2){
        uint2 o;
        o.x = pk2(acc[m][n][0], acc[m][n][1]);
        o.y = pk2(acc[m][n][2], acc[m][n][3]);
        *(uint2*)((u16*)Cb + (size_t)(rowb >> 8)*131072 + (size_t)col*256 + (rowb & 255)) = o;
      } else if (outm == 0){
        #pragma unroll
        for (int rr = 0; rr < 4; rr++)
          ((float*)Cb)[(size_t)(rowb + rr)*N + col] = acc[m][n][rr];
      } else {
        #pragma unroll
        for (int rr = 0; rr < 4; rr++){
          float v = acc[m][n][rr];
          if (BIAS) v += bias[col];
          if (ACT)  v = gelu_f(v);
          ((u16*)Cb)[(size_t)(rowb + rr)*N + col] = f2b(v);
        }
      }
    }
  }
}

template<int BIAS,int ACT>
__global__ __launch_bounds__(256) void gemm128_k(const u16* __restrict__ A,
                                                 const u16* __restrict__ Bt,
                                                 const float* __restrict__ bias,
                                                 void* __restrict__ Cb, int N, int K)
{
  __shared__ u16 sm[32768];  // 64KB
  gemm128_core<BIAS,ACT>(A, Bt, bias, Cb, N, K, K, K, 1, sm,
                         blockIdx.y*128, blockIdx.x*128);
}

// merged Kg / Vt / ctx — all share A = inp_bf (L2-friendly), z selects B/C
__global__ __launch_bounds__(256) void gemm3_k(
    const u16* __restrict__ A,
    const u16* __restrict__ B0, u16* __restrict__ C0,
    const u16* __restrict__ B1, u16* __restrict__ C1,
    const u16* __restrict__ B2, u16* __restrict__ C2)
{
  __shared__ u16 sm[32768];
  const u16 *Bt; u16* Cb; int outm = 1;
  if (blockIdx.z == 0){ Bt = B0; Cb = C0; }
  else if (blockIdx.z == 1){ Bt = B1; Cb = C1; outm = 2; }
  else { Bt = B2; Cb = C2; }
  gemm128_core<0,0>(A, Bt, nullptr, Cb, 512, 512, 512, 512, outm, sm,
                    blockIdx.y*128, blockIdx.x*128);
}

// split-K w2: K=2048 split in 2, f32 partials P[z][4096][512]  (R7 proven)
__global__ __launch_bounds__(256) void gemm_w2sk(const u16* __restrict__ G,
                                                 const u16* __restrict__ w2t,
                                                 float* __restrict__ P)
{
  __shared__ u16 sm[32768];
  const int z = blockIdx.z;
  gemm128_core<0,0>(G + z*1024, w2t + z*1024, nullptr,
                    (void*)(P + (size_t)z*NT*512), 512, 1024, 2048, 2048, 0,
                    sm, blockIdx.y*128, blockIdx.x*128);
}

// ---------------------------------------------------------------------------
// gemm64: 64x64 tile, acc[2][2], 2-buffer (32KB). bf16 out. (R7 proven)
// ---------------------------------------------------------------------------
__global__ __launch_bounds__(256) void gemm64_k(const u16* __restrict__ A,
                                                const u16* __restrict__ Bt,
                                                u16* __restrict__ Cb, int N, int K)
{
  __shared__ u16 sm[16384];
  const int tid = threadIdx.x;
  const int w = tid >> 6, l = tid & 63;
  const int wr = w >> 1, wc = w & 1;
  const int l15 = l & 15, lk = (l >> 4)*16;
  const int row0 = blockIdx.y*64, col0 = blockIdx.x*64;
  const int srow = tid >> 3;
  const int scol = (((tid & 7)*16) ^ ((srow & 7) << 4)) >> 1;
  const u16* pa = A  + (size_t)(row0 + srow)*K + scol;
  const u16* pb = Bt + (size_t)(col0 + srow)*K + scol;
  char* lA = (char*)sm + (tid & ~63)*16;

  f32x4 acc[2][2] = {};
  const int nt = K >> 6;
  auto STAGE = [&](int buf, int kt){
    char* a = lA + buf*8192;
    char* b = lA + 16384 + buf*8192;
    gl16(pa + kt,                a);
    gl16(pa + kt + (size_t)32*K, a + 4096);
    gl16(pb + kt,                b);
    gl16(pb + kt + (size_t)32*K, b + 4096);
  };
  STAGE(0, 0);
  __syncthreads();
  for (int t = 0; t < nt; ++t){
    if (t + 1 < nt) STAGE((t+1) & 1, (t+1)*64);
    const char* bA = (const char*)sm + (t&1)*8192;
    const char* bB = (const char*)sm + 16384 + (t&1)*8192;
    #pragma unroll
    for (int ks = 0; ks < 2; ks++){
      bf16x8 af[2], bv[2];
      #pragma unroll
      for (int m = 0; m < 2; m++){
        int r = wr*32 + m*16 + l15;
        af[m] = *(const bf16x8*)(bA + r*128 + ((ks*64 + lk) ^ ((r & 7) << 4)));
      }
      #pragma unroll
      for (int n = 0; n < 2; n++){
        int r = wc*32 + n*16 + l15;
        bv[n] = *(const bf16x8*)(bB + r*128 + ((ks*64 + lk) ^ ((r & 7) << 4)));
      }
      #pragma unroll
      for (int m = 0; m < 2; m++)
        #pragma unroll
        for (int n = 0; n < 2; n++)
          acc[m][n] = __builtin_amdgcn_mfma_f32_16x16x32_bf16(af[m], bv[n], acc[m][n], 0, 0, 0);
    }
    __syncthreads();
  }
  #pragma unroll
  for (int m = 0; m < 2; m++){
    #pragma unroll
    for (int n = 0; n < 2; n++){
      int col = col0 + wc*32 + n*16 + l15;
      int rowb = row0 + wr*32 + m*16 + (l >> 4)*4;
      #pragma unroll
      for (int rr = 0; rr < 4; rr++)
        Cb[(size_t)(rowb + rr)*N + col] = f2b(acc[m][n][rr]);
    }
  }
}

// ---------------------------------------------------------------------------
// qattn: fused Q-GEMM (64x64 tile, B = conv2-folded Wq2) + MFMA flash attn.
// grid (8 heads, 64 token-tiles). LDS 80KB (R7 proven):
//  [0,32K) gemm staging -> reused as K [256 key][64 d]
//  [32K,40K) Q tile [64 q][64 d]   [40K,72K) V [64 d][256 t]   [72K,80K) P
// ---------------------------------------------------------------------------
__global__ __launch_bounds__(256) void qattn_k(const u16* __restrict__ X1,
                                               const u16* __restrict__ Wq2,
                                               const u16* __restrict__ Kg,
                                               const u16* __restrict__ Vt,
                                               u16* __restrict__ O)
{
  __shared__ u16 sm[40960];   // 80KB
  const int h = blockIdx.x, ty = blockIdx.y;
  const int b = ty >> 2, bh = b*8 + h;
  const int tid = threadIdx.x;
  const int w = tid >> 6, l = tid & 63;
  const int l15 = l & 15, lg = l >> 4;
  const int wr = w >> 1, wc = w & 1;
  const int lk = lg*16;

  // V prefetch (8 gl16/thread) into [40K,72K): rows = d (512B), swizzled
  {
    const int vrow = tid >> 5;
    const int vcb  = (tid*16) & 511;
    const int scolV = (vcb ^ ((vrow & 7) << 4)) >> 1;
    const u16* pv = Vt + (size_t)bh*16384 + (size_t)vrow*256 + scolV;
    char* lV = (char*)sm + 40960 + (tid & ~63)*16;
    #pragma unroll
    for (int c = 0; c < 8; c++)
      gl16(pv + (size_t)(c*8)*256, lV + c*4096);
  }

  // ---- Q GEMM: Q = X1[ty*64..+64] @ Wq2[h*64..+64]^T, K=512 ----
  const int srow = tid >> 3;
  const int scol = (((tid & 7)*16) ^ ((srow & 7) << 4)) >> 1;
  const u16* pa = X1 + (size_t)(ty*64 + srow)*512 + scol;
  const u16* pb = Wq2 + (size_t)(h*64 + srow)*512 + scol;
  char* lS = (char*)sm + (tid & ~63)*16;

  auto QSTG = [&](int buf, int kt){
    char* a = lS + buf*8192;
    char* bq = lS + 16384 + buf*8192;
    gl16(pa + kt,              a);
    gl16(pa + kt + 32*512,     a + 4096);
    gl16(pb + kt,              bq);
    gl16(pb + kt + 32*512,     bq + 4096);
  };

  f32x4 qacc[2][2] = {};
  QSTG(0, 0);
  __syncthreads();
  for (int t = 0; t < 8; ++t){
    if (t < 7) QSTG((t+1) & 1, (t+1)*64);
    const char* bA = (const char*)sm + (t&1)*8192;
    const char* bB = (const char*)sm + 16384 + (t&1)*8192;
    #pragma unroll
    for (int ks = 0; ks < 2; ks++){
      bf16x8 af[2], bv[2];
      #pragma unroll
      for (int m = 0; m < 2; m++){
        int r = wr*32 + m*16 + l15;
        af[m] = *(const bf16x8*)(bA + r*128 + ((ks*64 + lk) ^ ((r & 7) << 4)));
      }
      #pragma unroll
      for (int n = 0; n < 2; n++){
        int r = wc*32 + n*16 + l15;
        bv[n] = *(const bf16x8*)(bB + r*128 + ((ks*64 + lk) ^ ((r & 7) << 4)));
      }
      #pragma unroll
      for (int m = 0; m < 2; m++)
        #pragma unroll
        for (int n = 0; n < 2; n++)
          qacc[m][n] = __builtin_amdgcn_mfma_f32_16x16x32_bf16(af[m], bv[n], qacc[m][n], 0, 0, 0);
    }
    __syncthreads();
  }

  // stage K into retired staging region [0,32K)
  {
    const u16* pk = Kg + (size_t)(b*256 + srow)*512 + h*64 + scol;
    char* lK = (char*)sm + (tid & ~63)*16;
    #pragma unroll
    for (int c = 0; c < 8; c++)
      gl16(pk + (size_t)(c*32)*512, lK + c*4096);
  }
  // write Q tile (bf16, swizzled) to [32K,40K)
  #pragma unroll
  for (int m = 0; m < 2; m++)
    #pragma unroll
    for (int n = 0; n < 2; n++)
      #pragma unroll
      for (int rr = 0; rr < 4; rr++){
        int row = wr*32 + m*16 + (l >> 4)*4 + rr;
        int col = wc*32 + n*16 + l15;
        *(u16*)((char*)sm + 32768 + row*128 + ((col*2) ^ ((row & 7) << 4))) = f2b(qacc[m][n][rr]);
      }
  __syncthreads();   // Q visible; implicit vmcnt(0) also lands K and V

  // ---- attention ----
  const int qt0 = b*256 + (ty & 3)*64 + w*16;
  bf16x8 aq[2];
  #pragma unroll
  for (int ks = 0; ks < 2; ks++){
    int qr = w*16 + l15;
    aq[ks] = *(const bf16x8*)((char*)sm + 32768 + qr*128 + ((ks*64 + lk) ^ ((qr & 7) << 4)));
  }
  char* Pw = (char*)sm + 73728 + w*2048;

  f32x4 oacc[4] = {};
  float rsum[4] = {0.f, 0.f, 0.f, 0.f};

  #pragma unroll
  for (int c = 0; c < 4; c++){
    f32x4 sacc[4] = {};
    #pragma unroll
    for (int n = 0; n < 4; n++){
      int r = c*64 + n*16 + l15;
      #pragma unroll
      for (int ks = 0; ks < 2; ks++){
        bf16x8 bk = *(const bf16x8*)((const char*)sm + r*128 + ((ks*64 + lk) ^ ((r & 7) << 4)));
        sacc[n] = __builtin_amdgcn_mfma_f32_16x16x32_bf16(aq[ks], bk, sacc[n], 0, 0, 0);
      }
    }
    #pragma unroll
    for (int n = 0; n < 4; n++){
      #pragma unroll
      for (int rr = 0; rr < 4; rr++){
        float p = __expf(sacc[n][rr]*0.125f);
        rsum[rr] += p;
        int q = lg*4 + rr, key = n*16 + l15;
        *(u16*)(Pw + ((q*128 + key*2) ^ ((q & 7) << 4))) = f2b(p);
      }
    }
    bf16x8 ap[2];
    #pragma unroll
    for (int ks2 = 0; ks2 < 2; ks2++)
      ap[ks2] = *(const bf16x8*)(Pw + l15*128 + ((ks2*64 + lk) ^ ((l15 & 7) << 4)));
    #pragma unroll
    for (int n = 0; n < 4; n++){
      int r = n*16 + l15;   // d index
      #pragma unroll
      for (int ks2 = 0; ks2 < 2; ks2++){
        bf16x8 bvv = *(const bf16x8*)((const char*)sm + 40960 + r*512 +
                                      ((c*128 + ks2*64 + lk) ^ ((r & 7) << 4)));
        oacc[n] = __builtin_amdgcn_mfma_f32_16x16x32_bf16(ap[ks2], bvv, oacc[n], 0, 0, 0);
      }
    }
  }

  #pragma unroll
  for (int m = 1; m < 16; m <<= 1){
    #pragma unroll
    for (int rr = 0; rr < 4; rr++) rsum[rr] += __shfl_xor(rsum[rr], m);
  }
  #pragma unroll
  for (int n = 0; n < 4; n++){
    int d = h*64 + n*16 + l15;
    #pragma unroll
    for (int rr = 0; rr < 4; rr++){
      int t = qt0 + lg*4 + rr;
      O[(size_t)t*ND + d] = f2b(oacc[n][rr]/rsum[rr]);
    }
  }
}

// ---------------------------------------------------------------------------
// fused residual-add + LayerNorm (D=512).
// MODE0: a=bf16, b=f32 -> bf.   MODE1: a=bf16, b=bf16 -> bf + hn rows (f32 a).
// MODE3: a=P0 f32, a2=P1 f32, bias2; b=bf16 -> f32 (split-K reduce fused).
// ---------------------------------------------------------------------------
template<int MODE>
__global__ __launch_bounds__(256) void ln_k(const void* __restrict__ aptr,
                                            const void* __restrict__ bptr,
                                            const float* __restrict__ g,
                                            const float* __restrict__ be,
                                            const float* __restrict__ a2,
                                            const float* __restrict__ bias2,
                                            u16* __restrict__ obf,
                                            float* __restrict__ of32,
                                            float* __restrict__ hnout)
{
  __shared__ float red[10];
  const int r0 = blockIdx.x, tid = threadIdx.x;
  const size_t base = (size_t)r0*ND;
  const int d = tid*2;
  float v0, v1;
  if (MODE == 3){
    float2 p0 = *(const float2*)((const float*)aptr + base + d);
    float2 p1 = *(const float2*)(a2 + base + d);
    u32 bv = *(const u32*)((const u16*)bptr + base + d);
    v0 = p0.x + p1.x + bias2[d]   + blo(bv);
    v1 = p0.y + p1.y + bias2[d+1] + bhi(bv);
  } else {
    u32 av = *(const u32*)((const u16*)aptr + base + d);
    v0 = blo(av); v1 = bhi(av);
    if (MODE == 1 && (r0 & 255) == 255){
      hnout[(size_t)(r0 >> 8)*512 + d]     = v0;
      hnout[(size_t)(r0 >> 8)*512 + d + 1] = v1;
    }
    if (MODE == 0){
      float2 bv = *(const float2*)((const float*)bptr + base + d);
      v0 += bv.x; v1 += bv.y;
    } else {
      u32 bv = *(const u32*)((const u16*)bptr + base + d);
      v0 += blo(bv); v1 += bhi(bv);
    }
  }
  float s = v0+v1, ss = v0*v0+v1*v1;
  #pragma unroll
  for (int m = 1; m < 64; m <<= 1){ s += __shfl_xor(s, m); ss += __shfl_xor(ss, m); }
  int wv = tid >> 6;
  if ((tid & 63) == 0){ red[wv] = s; red[4+wv] = ss; }
  __syncthreads();
  if (tid == 0){
    float S = red[0]+red[1]+red[2]+red[3];
    float SS = red[4]+red[5]+red[6]+red[7];
    float mu = S*(1.f/ND);
    float var = SS*(1.f/ND) - mu*mu;
    red[8] = mu; red[9] = rsqrtf(var + 1e-5f);
  }
  __syncthreads();
  float mu = red[8], rsd = red[9];
  float o0 = (v0-mu)*rsd*g[d]   + be[d];
  float o1 = (v1-mu)*rsd*g[d+1] + be[d+1];
  if (MODE == 3){
    *(float2*)(of32 + base + d) = make_float2(o0, o1);
  } else {
    *(u32*)(obf + base + d) = pk2(o0, o1);
  }
}

// ---------------------------------------------------------------------------
extern "C" void kernel_launch(void* const* d_in, const int* in_sizes, int n_in,
                              void* d_out, int out_size, void* d_ws, size_t ws_size,
                              hipStream_t stream) {
  const float* inp     = (const float*)d_in[0];
  const float* conv1_w = (const float*)d_in[1];
  const float* conv2_w = (const float*)d_in[2];
  const float* ctx_wq  = (const float*)d_in[3];
  // d_in[4] = ctx_wk : provably unused (softmax over singleton key axis == 1)
  const float* ctx_fc  = (const float*)d_in[5];
  const float* glb_wq  = (const float*)d_in[6];
  const float* glb_wk  = (const float*)d_in[7];
  const float* glb_fc  = (const float*)d_in[8];
  const float* ln1_g = (const float*)d_in[9],  *ln1_b = (const float*)d_in[10];
  const float* ln2_g = (const float*)d_in[11], *ln2_b = (const float*)d_in[12];
  const float* ln3_g = (const float*)d_in[13], *ln3_b = (const float*)d_in[14];
  const float* mlp_w1 = (const float*)d_in[15], *mlp_b1 = (const float*)d_in[16];
  const float* mlp_w2 = (const float*)d_in[17], *mlp_b2 = (const float*)d_in[18];
  float* out = (float*)d_out;
  float* hn  = out + (size_t)NT*ND;

  u16* wk_t   = (u16*)d_ws;
  u16* wq_t   = wk_t   + 262144;
  u16* wq2_t  = wq_t   + 262144;     // conv2-folded glb_wq (for Q)
  u16* gfc_t  = wq2_t  + 262144;
  u16* cfc_t  = gfc_t  + 262144;     // ctx_fc transposed
  u16* cwq1   = cfc_t  + 262144;     // conv1-folded ctx_wq, row-major [e][m]
  u16* Wc_t   = cwq1   + 262144;     // fold product, [n][e]
  u16* w1_t   = Wc_t   + 262144;     // 2048x512
  u16* w2_t   = w1_t   + 1048576;    // 512x2048
  u16* inp_bf = w2_t   + 1048576;
  u16* Abf    = inp_bf + 2097152;    // O
  u16* Cbf    = Abf    + 2097152;    // ctx -> HH
  u16* Kg     = Cbf    + 2097152;
  u16* Vt     = Kg     + 2097152;    // [b][h*64+d][t&255]
  u16* X1bf   = Vt     + 2097152;
  u16* X3bf   = X1bf   + 2097152;
  u16* Gbf    = X3bf   + 2097152;    // 4096x2048
  float* Pf   = (float*)(Gbf + 8388608);  // 2 x 4096 x 512 f32 split-K partials

  // pack: weight trs + conv2-folded wq2 + conv1-folded cwq1 + inp->bf16
  pack_k<<<1984, 256, 0, stream>>>(inp, ctx_wq, ctx_fc, glb_wq, glb_wk, glb_fc,
                                   mlp_w1, mlp_w2, conv1_w, conv2_w,
                                   wk_t, wq_t, wq2_t, gfc_t, cfc_t, cwq1,
                                   w1_t, w2_t, inp_bf);
  // Wc fold (MFMA): Wc_t[n][e] = sum_m cfc_t[n][m] * cwq1[e][m]
  gemm64_k<<<dim3(8,8),256,0,stream>>>(cfc_t, cwq1, Wc_t, 512, 512);
  // Kg, Vt, ctx in one dispatch; all A = inp_bf (L2-shared)
  gemm3_k<<<dim3(4,32,3),256,0,stream>>>(inp_bf, wk_t, Kg, wq_t, Vt, Wc_t, Cbf);
  // LN1: X1 = LN(ctx + inp)
  ln_k<0><<<NT,256,0,stream>>>(Cbf, inp, ln1_g, ln1_b, nullptr, nullptr,
                               X1bf, nullptr, nullptr);
  // fused Q-gemm (X1 @ Wq2) + attention -> O (Abf)
  qattn_k<<<dim3(8,64),256,0,stream>>>(X1bf, wq2_t, Kg, Vt, Abf);
  // HH = O @ glb_fc
  gemm64_k<<<dim3(8,64),256,0,stream>>>(Abf, gfc_t, Cbf, 512, 512);
  // LN2 (+X1) -> X3bf, fused hn extraction
  ln_k<1><<<NT,256,0,stream>>>(Cbf, X1bf, ln2_g, ln2_b, nullptr, nullptr,
                               X3bf, nullptr, hn);
  // MLP: w1 128x128 (512 blocks); w2 split-K2 f32 partials (256 blocks)
  gemm128_k<1,1><<<dim3(16,32),256,0,stream>>>(X3bf, w1_t, mlp_b1, Gbf, 2048, 512);
  gemm_w2sk<<<dim3(4,32,2),256,0,stream>>>(Gbf, w2_t, Pf);
  // LN3: out = LN(P0+P1+b2 + X3)
  ln_k<3><<<NT,256,0,stream>>>(Pf, X3bf, ln3_g, ln3_b, Pf + (size_t)NT*512,
                               mlp_b2, nullptr, out, nullptr);
}

// Round 13
// 95.678 us; speedup vs baseline: 1.7999x; 1.0581x over previous
//
#include <hip/hip_runtime.h>
#include <math.h>

#define NBS 16
#define NL 256
#define ND 512
#define NH 8
#define NDFF 2048
#define NT (NBS*NL)   // 4096 tokens

typedef unsigned short u16;
typedef unsigned int   u32;
typedef __attribute__((ext_vector_type(8))) short bf16x8;  // 8 bf16 = 4 VGPRs
typedef __attribute__((ext_vector_type(4))) float f32x4;

__device__ __forceinline__ u16 f2b(float f){
  u32 u = __float_as_uint(f);
  u32 r = u + 0x7FFFu + ((u >> 16) & 1u);
  return (u16)(r >> 16);
}
__device__ __forceinline__ float blo(u32 u){ return __uint_as_float(u << 16); }
__device__ __forceinline__ float bhi(u32 u){ return __uint_as_float(u & 0xFFFF0000u); }
__device__ __forceinline__ u32 pk2(float a, float b){ return (u32)f2b(a) | ((u32)f2b(b) << 16); }

// async global->LDS, 16B/lane; dest = wave-uniform base + lane*16
__device__ __forceinline__ void gl16(const void* g, void* l){
  __builtin_amdgcn_global_load_lds((const __attribute__((address_space(1))) void*)g,
                                   (__attribute__((address_space(3))) void*)l, 16, 0, 0);
}
__device__ __forceinline__ float gelu_f(float x){ return 0.5f*x*(1.f+erff(x*0.70710678118654752f)); }

// ---------------------------------------------------------------------------
// pack kernel (R12 proven):
//  - weight transpose+bf16 (Wt[N][K]) for glb_wk / glb_wq / glb_fc / ctx_fc / w1 / w2
//  - conv2-folded transpose of glb_wq -> wq2_t  (Q = X1 @ Wq2)
//  - conv1-folded ELEMENTWISE copy of ctx_wq -> cwq1 (row-major [e][m], bf16)
//  - inp -> bf16
// ---------------------------------------------------------------------------
__device__ inline void tr_tile(const float* __restrict__ src, u16* __restrict__ dst,
                               int K, int N, int ntk, int tb, float* Tsh){
  int tk = tb % ntk, tn = tb / ntk;
  int t = threadIdx.x;
  int r = t >> 2, q = t & 3;
  const float* s = src + (size_t)(tk*64 + r)*N + tn*64 + q*16;
  #pragma unroll
  for (int u2 = 0; u2 < 4; u2++){
    float4 v = *(const float4*)(s + u2*4);
    Tsh[r*65 + q*16 + u2*4 + 0] = v.x;
    Tsh[r*65 + q*16 + u2*4 + 1] = v.y;
    Tsh[r*65 + q*16 + u2*4 + 2] = v.z;
    Tsh[r*65 + q*16 + u2*4 + 3] = v.w;
  }
  __syncthreads();
  int n = t >> 2, kq = t & 3;
  u16* d = dst + (size_t)(tn*64 + n)*K + tk*64 + kq*16;
  u32 u[8];
  #pragma unroll
  for (int j = 0; j < 8; j++){
    u32 lo = f2b(Tsh[(kq*16 + 2*j    )*65 + n]);
    u32 hi = f2b(Tsh[(kq*16 + 2*j + 1)*65 + n]);
    u[j] = lo | (hi << 16);
  }
  ((uint4*)d)[0] = make_uint4(u[0],u[1],u[2],u[3]);
  ((uint4*)d)[1] = make_uint4(u[4],u[5],u[6],u[7]);
}

// transpose with conv fold along source-row axis (verified R11/R12)
__device__ inline void tr_tile_conv(const float* __restrict__ src, u16* __restrict__ dst,
                                    int tb, const float* __restrict__ cw, float* Tsh){
  int tk = tb & 7, tn = tb >> 3;   // 512x512
  int t = threadIdx.x;
  int r = t >> 2, q = t & 3;
  const float* s = src + (size_t)(tk*64 + r)*512 + tn*64 + q*16;
  #pragma unroll
  for (int u2 = 0; u2 < 4; u2++){
    float4 v = *(const float4*)(s + u2*4);
    Tsh[(r+1)*65 + q*16 + u2*4 + 0] = v.x;
    Tsh[(r+1)*65 + q*16 + u2*4 + 1] = v.y;
    Tsh[(r+1)*65 + q*16 + u2*4 + 2] = v.z;
    Tsh[(r+1)*65 + q*16 + u2*4 + 3] = v.w;
  }
  if (t < 64){
    Tsh[t] = (tk > 0) ? src[(size_t)(tk*64 - 1)*512 + tn*64 + t] : 0.f;
  } else if (t < 128){
    int tt = t - 64;
    Tsh[65*65 + tt] = (tk < 7) ? src[(size_t)(tk*64 + 64)*512 + tn*64 + tt] : 0.f;
  }
  __syncthreads();
  float c0 = cw[0], c1 = cw[1], c2 = cw[2];
  int n = t >> 2, kq = t & 3;
  u16* d = dst + (size_t)(tn*64 + n)*512 + tk*64 + kq*16;
  u32 u[8];
  #pragma unroll
  for (int j = 0; j < 8; j++){
    float lo = c0*Tsh[(kq*16 + 2*j + 2)*65 + n] + c1*Tsh[(kq*16 + 2*j + 1)*65 + n]
             + c2*Tsh[(kq*16 + 2*j    )*65 + n];
    float hi = c0*Tsh[(kq*16 + 2*j + 3)*65 + n] + c1*Tsh[(kq*16 + 2*j + 2)*65 + n]
             + c2*Tsh[(kq*16 + 2*j + 1)*65 + n];
    u[j] = pk2(lo, hi);
  }
  ((uint4*)d)[0] = make_uint4(u[0],u[1],u[2],u[3]);
  ((uint4*)d)[1] = make_uint4(u[4],u[5],u[6],u[7]);
}

__global__ __launch_bounds__(256) void pack_k(
    const float* __restrict__ inp,
    const float* __restrict__ ctx_wq, const float* __restrict__ ctx_fc,
    const float* __restrict__ glb_wq, const float* __restrict__ glb_wk,
    const float* __restrict__ glb_fc,
    const float* __restrict__ w1, const float* __restrict__ w2,
    const float* __restrict__ c1w, const float* __restrict__ c2w,
    u16* wk_t, u16* wq_t, u16* wq2_t, u16* gfc_t, u16* cfc_t, u16* cwq1,
    u16* w1_t, u16* w2_t, u16* inp_bf)
{
  __shared__ float Tsh[66*65];
  int bx = blockIdx.x, t = threadIdx.x;
  if (bx < 256){
    int m = bx >> 6, tb = bx & 63;
    const float* s; u16* d;
    if      (m == 0){ s = glb_wk; d = wk_t; }
    else if (m == 1){ s = glb_wq; d = wq_t; }
    else if (m == 2){ s = glb_fc; d = gfc_t; }
    else            { s = ctx_fc; d = cfc_t; }
    tr_tile(s, d, 512, 512, 8, tb, Tsh);
  } else if (bx < 320){
    tr_tile_conv(glb_wq, wq2_t, bx - 256, c2w, Tsh);
  } else if (bx < 576){
    tr_tile(w1, w1_t, 512, 2048, 8, bx - 320, Tsh);
  } else if (bx < 832){
    tr_tile(w2, w2_t, 2048, 512, 32, bx - 576, Tsh);
  } else if (bx < 1856){
    size_t i0 = (size_t)(bx - 832)*2048 + (size_t)t*8;
    float4 v0 = *(const float4*)(inp + i0);
    float4 v1 = *(const float4*)(inp + i0 + 4);
    uint4 o;
    o.x = pk2(v0.x, v0.y); o.y = pk2(v0.z, v0.w);
    o.z = pk2(v1.x, v1.y); o.w = pk2(v1.z, v1.w);
    *(uint4*)(inp_bf + i0) = o;
  } else {
    // conv1-folded elementwise copy of ctx_wq
    size_t i0 = (size_t)(bx - 1856)*2048 + (size_t)t*8;
    int e = (int)(i0 >> 9);
    float c0 = c1w[0], c1 = c1w[1], c2 = c1w[2];
    float4 a0 = *(const float4*)(ctx_wq + i0);
    float4 a1 = *(const float4*)(ctx_wq + i0 + 4);
    float4 p0 = make_float4(0,0,0,0), p1 = p0, m0 = p0, m1 = p0;
    if (e < 511){ p0 = *(const float4*)(ctx_wq + i0 + 512); p1 = *(const float4*)(ctx_wq + i0 + 516); }
    if (e > 0)  { m0 = *(const float4*)(ctx_wq + i0 - 512); m1 = *(const float4*)(ctx_wq + i0 - 508); }
    uint4 o;
    o.x = pk2(c0*p0.x + c1*a0.x + c2*m0.x, c0*p0.y + c1*a0.y + c2*m0.y);
    o.y = pk2(c0*p0.z + c1*a0.z + c2*m0.z, c0*p0.w + c1*a0.w + c2*m0.w);
    o.z = pk2(c0*p1.x + c1*a1.x + c2*m1.x, c0*p1.y + c1*a1.y + c2*m1.y);
    o.w = pk2(c0*p1.z + c1*a1.z + c2*m1.z, c0*p1.w + c1*a1.w + c2*m1.w);
    *(uint4*)(cwq1 + i0) = o;
  }
}

// ---------------------------------------------------------------------------
// gemm128 (8-wave): C = A[M][lda]*Bt[N][ldb]^T, tile 128x128, BK=64,
// 512 threads = 8 waves (2 row x 4 col), wave tile 64x32 = acc[4][2].
// 2-buffer LDS (64KB), prefetch-before-compute, one __syncthreads per
// K-step (R7 proven loop). XOR swizzle (rule #21). 2 blocks/CU x 8 waves
// = 16 waves/CU (was 8).
// outm: 0=f32, 1=bf16(+bias/act), 2=Vt-transpose.
// ---------------------------------------------------------------------------
template<int BIAS,int ACT>
__device__ __forceinline__ void gemm128_core(const u16* __restrict__ A,
    const u16* __restrict__ Bt, const float* __restrict__ bias,
    void* __restrict__ Cb, int N, int K, int lda, int ldb, int outm,
    u16* sm, int row0, int col0)
{
  const int tid = threadIdx.x;           // 0..511
  const int w = tid >> 6, l = tid & 63;
  const int wr = w >> 2, wc = w & 3;     // 2 x 4 waves
  const int l15 = l & 15, lk = (l >> 4)*16;
  const int srow = tid >> 3;             // 0..63
  const int scol = (((tid & 7)*16) ^ ((srow & 7) << 4)) >> 1;
  const u16* pa = A  + (size_t)(row0 + srow)*lda + scol;
  const u16* pb = Bt + (size_t)(col0 + srow)*ldb + scol;
  char* lA = (char*)sm + (tid & ~63)*16;            // A bufs at 0, 16384 (8KB/round)
  char* lB = (char*)sm + 32768 + (tid & ~63)*16;    // B bufs at 32768, 49152

  f32x4 acc[4][2] = {};
  const int nt = K >> 6;

  auto STAGE = [&](int buf, int kt){
    char* a = lA + buf*16384;
    char* b = lB + buf*16384;
    #pragma unroll
    for (int i = 0; i < 2; i++){
      gl16(pa + kt + (size_t)(i*64)*lda, a + i*8192);
      gl16(pb + kt + (size_t)(i*64)*ldb, b + i*8192);
    }
  };

  STAGE(0, 0);
  __syncthreads();
  for (int t = 0; t < nt; ++t){
    if (t + 1 < nt) STAGE((t+1) & 1, (t+1)*64);
    const char* bA = (const char*)sm + (t&1)*16384;
    const char* bB = (const char*)sm + 32768 + (t&1)*16384;
    #pragma unroll
    for (int ks = 0; ks < 2; ks++){
      bf16x8 af[4], bv[2];
      #pragma unroll
      for (int m = 0; m < 4; m++){
        int r = wr*64 + m*16 + l15;
        af[m] = *(const bf16x8*)(bA + r*128 + ((ks*64 + lk) ^ ((r & 7) << 4)));
      }
      #pragma unroll
      for (int n = 0; n < 2; n++){
        int r = wc*32 + n*16 + l15;
        bv[n] = *(const bf16x8*)(bB + r*128 + ((ks*64 + lk) ^ ((r & 7) << 4)));
      }
      #pragma unroll
      for (int m = 0; m < 4; m++)
        #pragma unroll
        for (int n = 0; n < 2; n++)
          acc[m][n] = __builtin_amdgcn_mfma_f32_16x16x32_bf16(af[m], bv[n], acc[m][n], 0, 0, 0);
    }
    __syncthreads();
  }

  #pragma unroll
  for (int m = 0; m < 4; m++){
    #pragma unroll
    for (int n = 0; n < 2; n++){
      int col = col0 + wc*32 + n*16 + l15;
      int rowb = row0 + wr*64 + m*16 + (l >> 4)*4;
      if (outm == 2){
        uint2 o;
        o.x = pk2(acc[m][n][0], acc[m][n][1]);
        o.y = pk2(acc[m][n][2], acc[m][n][3]);
        *(uint2*)((u16*)Cb + (size_t)(rowb >> 8)*131072 + (size_t)col*256 + (rowb & 255)) = o;
      } else if (outm == 0){
        #pragma unroll
        for (int rr = 0; rr < 4; rr++)
          ((float*)Cb)[(size_t)(rowb + rr)*N + col] = acc[m][n][rr];
      } else {
        #pragma unroll
        for (int rr = 0; rr < 4; rr++){
          float v = acc[m][n][rr];
          if (BIAS) v += bias[col];
          if (ACT)  v = gelu_f(v);
          ((u16*)Cb)[(size_t)(rowb + rr)*N + col] = f2b(v);
        }
      }
    }
  }
}

template<int BIAS,int ACT>
__global__ __launch_bounds__(512) void gemm128_k(const u16* __restrict__ A,
                                                 const u16* __restrict__ Bt,
                                                 const float* __restrict__ bias,
                                                 void* __restrict__ Cb, int N, int K)
{
  __shared__ u16 sm[32768];  // 64KB
  gemm128_core<BIAS,ACT>(A, Bt, bias, Cb, N, K, K, K, 1, sm,
                         blockIdx.y*128, blockIdx.x*128);
}

// merged Kg / Vt / ctx — all share A = inp_bf (L2-friendly), z selects B/C
__global__ __launch_bounds__(512) void gemm3_k(
    const u16* __restrict__ A,
    const u16* __restrict__ B0, u16* __restrict__ C0,
    const u16* __restrict__ B1, u16* __restrict__ C1,
    const u16* __restrict__ B2, u16* __restrict__ C2)
{
  __shared__ u16 sm[32768];
  const u16 *Bt; u16* Cb; int outm = 1;
  if (blockIdx.z == 0){ Bt = B0; Cb = C0; }
  else if (blockIdx.z == 1){ Bt = B1; Cb = C1; outm = 2; }
  else { Bt = B2; Cb = C2; }
  gemm128_core<0,0>(A, Bt, nullptr, Cb, 512, 512, 512, 512, outm, sm,
                    blockIdx.y*128, blockIdx.x*128);
}

// split-K4 w2: K=2048 split in 4, bf16 partials P4[z][4096][512] (R10 proven
// absmax-neutral). 512 blocks = 2/CU x 8 waves.
__global__ __launch_bounds__(512) void gemm_w2sk(const u16* __restrict__ G,
                                                 const u16* __restrict__ w2t,
                                                 u16* __restrict__ P4)
{
  __shared__ u16 sm[32768];
  const int z = blockIdx.z;
  gemm128_core<0,0>(G + z*512, w2t + z*512, nullptr,
                    (void*)(P4 + (size_t)z*NT*512), 512, 512, 2048, 2048, 1,
                    sm, blockIdx.y*128, blockIdx.x*128);
}

// ---------------------------------------------------------------------------
// gemm64: 64x64 tile, acc[2][2], 2-buffer (32KB). bf16 out. (R7 proven)
// ---------------------------------------------------------------------------
__global__ __launch_bounds__(256) void gemm64_k(const u16* __restrict__ A,
                                                const u16* __restrict__ Bt,
                                                u16* __restrict__ Cb, int N, int K)
{
  __shared__ u16 sm[16384];
  const int tid = threadIdx.x;
  const int w = tid >> 6, l = tid & 63;
  const int wr = w >> 1, wc = w & 1;
  const int l15 = l & 15, lk = (l >> 4)*16;
  const int row0 = blockIdx.y*64, col0 = blockIdx.x*64;
  const int srow = tid >> 3;
  const int scol = (((tid & 7)*16) ^ ((srow & 7) << 4)) >> 1;
  const u16* pa = A  + (size_t)(row0 + srow)*K + scol;
  const u16* pb = Bt + (size_t)(col0 + srow)*K + scol;
  char* lA = (char*)sm + (tid & ~63)*16;

  f32x4 acc[2][2] = {};
  const int nt = K >> 6;
  auto STAGE = [&](int buf, int kt){
    char* a = lA + buf*8192;
    char* b = lA + 16384 + buf*8192;
    gl16(pa + kt,                a);
    gl16(pa + kt + (size_t)32*K, a + 4096);
    gl16(pb + kt,                b);
    gl16(pb + kt + (size_t)32*K, b + 4096);
  };
  STAGE(0, 0);
  __syncthreads();
  for (int t = 0; t < nt; ++t){
    if (t + 1 < nt) STAGE((t+1) & 1, (t+1)*64);
    const char* bA = (const char*)sm + (t&1)*8192;
    const char* bB = (const char*)sm + 16384 + (t&1)*8192;
    #pragma unroll
    for (int ks = 0; ks < 2; ks++){
      bf16x8 af[2], bv[2];
      #pragma unroll
      for (int m = 0; m < 2; m++){
        int r = wr*32 + m*16 + l15;
        af[m] = *(const bf16x8*)(bA + r*128 + ((ks*64 + lk) ^ ((r & 7) << 4)));
      }
      #pragma unroll
      for (int n = 0; n < 2; n++){
        int r = wc*32 + n*16 + l15;
        bv[n] = *(const bf16x8*)(bB + r*128 + ((ks*64 + lk) ^ ((r & 7) << 4)));
      }
      #pragma unroll
      for (int m = 0; m < 2; m++)
        #pragma unroll
        for (int n = 0; n < 2; n++)
          acc[m][n] = __builtin_amdgcn_mfma_f32_16x16x32_bf16(af[m], bv[n], acc[m][n], 0, 0, 0);
    }
    __syncthreads();
  }
  #pragma unroll
  for (int m = 0; m < 2; m++){
    #pragma unroll
    for (int n = 0; n < 2; n++){
      int col = col0 + wc*32 + n*16 + l15;
      int rowb = row0 + wr*32 + m*16 + (l >> 4)*4;
      #pragma unroll
      for (int rr = 0; rr < 4; rr++)
        Cb[(size_t)(rowb + rr)*N + col] = f2b(acc[m][n][rr]);
    }
  }
}

// ---------------------------------------------------------------------------
// qattn: fused Q-GEMM (64x64 tile, B = conv2-folded Wq2) + MFMA flash attn.
// grid (8 heads, 64 token-tiles). LDS 80KB (R7 proven):
//  [0,32K) gemm staging -> reused as K [256 key][64 d]
//  [32K,40K) Q tile [64 q][64 d]   [40K,72K) V [64 d][256 t]   [72K,80K) P
// ---------------------------------------------------------------------------
__global__ __launch_bounds__(256) void qattn_k(const u16* __restrict__ X1,
                                               const u16* __restrict__ Wq2,
                                               const u16* __restrict__ Kg,
                                               const u16* __restrict__ Vt,
                                               u16* __restrict__ O)
{
  __shared__ u16 sm[40960];   // 80KB
  const int h = blockIdx.x, ty = blockIdx.y;
  const int b = ty >> 2, bh = b*8 + h;
  const int tid = threadIdx.x;
  const int w = tid >> 6, l = tid & 63;
  const int l15 = l & 15, lg = l >> 4;
  const int wr = w >> 1, wc = w & 1;
  const int lk = lg*16;

  // V prefetch (8 gl16/thread) into [40K,72K): rows = d (512B), swizzled
  {
    const int vrow = tid >> 5;
    const int vcb  = (tid*16) & 511;
    const int scolV = (vcb ^ ((vrow & 7) << 4)) >> 1;
    const u16* pv = Vt + (size_t)bh*16384 + (size_t)vrow*256 + scolV;
    char* lV = (char*)sm + 40960 + (tid & ~63)*16;
    #pragma unroll
    for (int c = 0; c < 8; c++)
      gl16(pv + (size_t)(c*8)*256, lV + c*4096);
  }

  // ---- Q GEMM: Q = X1[ty*64..+64] @ Wq2[h*64..+64]^T, K=512 ----
  const int srow = tid >> 3;
  const int scol = (((tid & 7)*16) ^ ((srow & 7) << 4)) >> 1;
  const u16* pa = X1 + (size_t)(ty*64 + srow)*512 + scol;
  const u16* pb = Wq2 + (size_t)(h*64 + srow)*512 + scol;
  char* lS = (char*)sm + (tid & ~63)*16;

  auto QSTG = [&](int buf, int kt){
    char* a = lS + buf*8192;
    char* bq = lS + 16384 + buf*8192;
    gl16(pa + kt,              a);
    gl16(pa + kt + 32*512,     a + 4096);
    gl16(pb + kt,              bq);
    gl16(pb + kt + 32*512,     bq + 4096);
  };

  f32x4 qacc[2][2] = {};
  QSTG(0, 0);
  __syncthreads();
  for (int t = 0; t < 8; ++t){
    if (t < 7) QSTG((t+1) & 1, (t+1)*64);
    const char* bA = (const char*)sm + (t&1)*8192;
    const char* bB = (const char*)sm + 16384 + (t&1)*8192;
    #pragma unroll
    for (int ks = 0; ks < 2; ks++){
      bf16x8 af[2], bv[2];
      #pragma unroll
      for (int m = 0; m < 2; m++){
        int r = wr*32 + m*16 + l15;
        af[m] = *(const bf16x8*)(bA + r*128 + ((ks*64 + lk) ^ ((r & 7) << 4)));
      }
      #pragma unroll
      for (int n = 0; n < 2; n++){
        int r = wc*32 + n*16 + l15;
        bv[n] = *(const bf16x8*)(bB + r*128 + ((ks*64 + lk) ^ ((r & 7) << 4)));
      }
      #pragma unroll
      for (int m = 0; m < 2; m++)
        #pragma unroll
        for (int n = 0; n < 2; n++)
          qacc[m][n] = __builtin_amdgcn_mfma_f32_16x16x32_bf16(af[m], bv[n], qacc[m][n], 0, 0, 0);
    }
    __syncthreads();
  }

  // stage K into retired staging region [0,32K)
  {
    const u16* pk = Kg + (size_t)(b*256 + srow)*512 + h*64 + scol;
    char* lK = (char*)sm + (tid & ~63)*16;
    #pragma unroll
    for (int c = 0; c < 8; c++)
      gl16(pk + (size_t)(c*32)*512, lK + c*4096);
  }
  // write Q tile (bf16, swizzled) to [32K,40K)
  #pragma unroll
  for (int m = 0; m < 2; m++)
    #pragma unroll
    for (int n = 0; n < 2; n++)
      #pragma unroll
      for (int rr = 0; rr < 4; rr++){
        int row = wr*32 + m*16 + (l >> 4)*4 + rr;
        int col = wc*32 + n*16 + l15;
        *(u16*)((char*)sm + 32768 + row*128 + ((col*2) ^ ((row & 7) << 4))) = f2b(qacc[m][n][rr]);
      }
  __syncthreads();   // Q visible; implicit vmcnt(0) also lands K and V

  // ---- attention ----
  const int qt0 = b*256 + (ty & 3)*64 + w*16;
  bf16x8 aq[2];
  #pragma unroll
  for (int ks = 0; ks < 2; ks++){
    int qr = w*16 + l15;
    aq[ks] = *(const bf16x8*)((char*)sm + 32768 + qr*128 + ((ks*64 + lk) ^ ((qr & 7) << 4)));
  }
  char* Pw = (char*)sm + 73728 + w*2048;

  f32x4 oacc[4] = {};
  float rsum[4] = {0.f, 0.f, 0.f, 0.f};

  #pragma unroll
  for (int c = 0; c < 4; c++){
    f32x4 sacc[4] = {};
    #pragma unroll
    for (int n = 0; n < 4; n++){
      int r = c*64 + n*16 + l15;
      #pragma unroll
      for (int ks = 0; ks < 2; ks++){
        bf16x8 bk = *(const bf16x8*)((const char*)sm + r*128 + ((ks*64 + lk) ^ ((r & 7) << 4)));
        sacc[n] = __builtin_amdgcn_mfma_f32_16x16x32_bf16(aq[ks], bk, sacc[n], 0, 0, 0);
      }
    }
    #pragma unroll
    for (int n = 0; n < 4; n++){
      #pragma unroll
      for (int rr = 0; rr < 4; rr++){
        float p = __expf(sacc[n][rr]*0.125f);
        rsum[rr] += p;
        int q = lg*4 + rr, key = n*16 + l15;
        *(u16*)(Pw + ((q*128 + key*2) ^ ((q & 7) << 4))) = f2b(p);
      }
    }
    bf16x8 ap[2];
    #pragma unroll
    for (int ks2 = 0; ks2 < 2; ks2++)
      ap[ks2] = *(const bf16x8*)(Pw + l15*128 + ((ks2*64 + lk) ^ ((l15 & 7) << 4)));
    #pragma unroll
    for (int n = 0; n < 4; n++){
      int r = n*16 + l15;   // d index
      #pragma unroll
      for (int ks2 = 0; ks2 < 2; ks2++){
        bf16x8 bvv = *(const bf16x8*)((const char*)sm + 40960 + r*512 +
                                      ((c*128 + ks2*64 + lk) ^ ((r & 7) << 4)));
        oacc[n] = __builtin_amdgcn_mfma_f32_16x16x32_bf16(ap[ks2], bvv, oacc[n], 0, 0, 0);
      }
    }
  }

  #pragma unroll
  for (int m = 1; m < 16; m <<= 1){
    #pragma unroll
    for (int rr = 0; rr < 4; rr++) rsum[rr] += __shfl_xor(rsum[rr], m);
  }
  #pragma unroll
  for (int n = 0; n < 4; n++){
    int d = h*64 + n*16 + l15;
    #pragma unroll
    for (int rr = 0; rr < 4; rr++){
      int t = qt0 + lg*4 + rr;
      O[(size_t)t*ND + d] = f2b(oacc[n][rr]/rsum[rr]);
    }
  }
}

// ---------------------------------------------------------------------------
// fused residual-add + LayerNorm (D=512).
// MODE0: a=bf16, b=f32 -> bf.   MODE1: a=bf16, b=bf16 -> bf + hn rows (f32 a).
// MODE3: a=P4 bf16 x4 partials, bias2; b=bf16 -> f32 (split-K reduce fused).
// ---------------------------------------------------------------------------
template<int MODE>
__global__ __launch_bounds__(256) void ln_k(const void* __restrict__ aptr,
                                            const void* __restrict__ bptr,
                                            const float* __restrict__ g,
                                            const float* __restrict__ be,
                                            const float* __restrict__ bias2,
                                            u16* __restrict__ obf,
                                            float* __restrict__ of32,
                                            float* __restrict__ hnout)
{
  __shared__ float red[10];
  const int r0 = blockIdx.x, tid = threadIdx.x;
  const size_t base = (size_t)r0*ND;
  const int d = tid*2;
  float v0, v1;
  if (MODE == 3){
    const u16* p4 = (const u16*)aptr;
    u32 q0 = *(const u32*)(p4 + base + d);
    u32 q1 = *(const u32*)(p4 + 2097152 + base + d);
    u32 q2 = *(const u32*)(p4 + 4194304 + base + d);
    u32 q3 = *(const u32*)(p4 + 6291456 + base + d);
    u32 bv = *(const u32*)((const u16*)bptr + base + d);
    v0 = blo(q0)+blo(q1)+blo(q2)+blo(q3) + bias2[d]   + blo(bv);
    v1 = bhi(q0)+bhi(q1)+bhi(q2)+bhi(q3) + bias2[d+1] + bhi(bv);
  } else {
    u32 av = *(const u32*)((const u16*)aptr + base + d);
    v0 = blo(av); v1 = bhi(av);
    if (MODE == 1 && (r0 & 255) == 255){
      hnout[(size_t)(r0 >> 8)*512 + d]     = v0;
      hnout[(size_t)(r0 >> 8)*512 + d + 1] = v1;
    }
    if (MODE == 0){
      float2 bv = *(const float2*)((const float*)bptr + base + d);
      v0 += bv.x; v1 += bv.y;
    } else {
      u32 bv = *(const u32*)((const u16*)bptr + base + d);
      v0 += blo(bv); v1 += bhi(bv);
    }
  }
  float s = v0+v1, ss = v0*v0+v1*v1;
  #pragma unroll
  for (int m = 1; m < 64; m <<= 1){ s += __shfl_xor(s, m); ss += __shfl_xor(ss, m); }
  int wv = tid >> 6;
  if ((tid & 63) == 0){ red[wv] = s; red[4+wv] = ss; }
  __syncthreads();
  if (tid == 0){
    float S = red[0]+red[1]+red[2]+red[3];
    float SS = red[4]+red[5]+red[6]+red[7];
    float mu = S*(1.f/ND);
    float var = SS*(1.f/ND) - mu*mu;
    red[8] = mu; red[9] = rsqrtf(var + 1e-5f);
  }
  __syncthreads();
  float mu = red[8], rsd = red[9];
  float o0 = (v0-mu)*rsd*g[d]   + be[d];
  float o1 = (v1-mu)*rsd*g[d+1] + be[d+1];
  if (MODE == 3){
    *(float2*)(of32 + base + d) = make_float2(o0, o1);
  } else {
    *(u32*)(obf + base + d) = pk2(o0, o1);
  }
}

// ---------------------------------------------------------------------------
extern "C" void kernel_launch(void* const* d_in, const int* in_sizes, int n_in,
                              void* d_out, int out_size, void* d_ws, size_t ws_size,
                              hipStream_t stream) {
  const float* inp     = (const float*)d_in[0];
  const float* conv1_w = (const float*)d_in[1];
  const float* conv2_w = (const float*)d_in[2];
  const float* ctx_wq  = (const float*)d_in[3];
  // d_in[4] = ctx_wk : provably unused (softmax over singleton key axis == 1)
  const float* ctx_fc  = (const float*)d_in[5];
  const float* glb_wq  = (const float*)d_in[6];
  const float* glb_wk  = (const float*)d_in[7];
  const float* glb_fc  = (const float*)d_in[8];
  const float* ln1_g = (const float*)d_in[9],  *ln1_b = (const float*)d_in[10];
  const float* ln2_g = (const float*)d_in[11], *ln2_b = (const float*)d_in[12];
  const float* ln3_g = (const float*)d_in[13], *ln3_b = (const float*)d_in[14];
  const float* mlp_w1 = (const float*)d_in[15], *mlp_b1 = (const float*)d_in[16];
  const float* mlp_w2 = (const float*)d_in[17], *mlp_b2 = (const float*)d_in[18];
  float* out = (float*)d_out;
  float* hn  = out + (size_t)NT*ND;

  u16* wk_t   = (u16*)d_ws;
  u16* wq_t   = wk_t   + 262144;
  u16* wq2_t  = wq_t   + 262144;     // conv2-folded glb_wq (for Q)
  u16* gfc_t  = wq2_t  + 262144;
  u16* cfc_t  = gfc_t  + 262144;     // ctx_fc transposed
  u16* cwq1   = cfc_t  + 262144;     // conv1-folded ctx_wq, row-major [e][m]
  u16* Wc_t   = cwq1   + 262144;     // fold product, [n][e]
  u16* w1_t   = Wc_t   + 262144;     // 2048x512
  u16* w2_t   = w1_t   + 1048576;    // 512x2048
  u16* inp_bf = w2_t   + 1048576;
  u16* Abf    = inp_bf + 2097152;    // O
  u16* Cbf    = Abf    + 2097152;    // ctx -> HH
  u16* Kg     = Cbf    + 2097152;
  u16* Vt     = Kg     + 2097152;    // [b][h*64+d][t&255]
  u16* X1bf   = Vt     + 2097152;
  u16* X3bf   = X1bf   + 2097152;
  u16* Gbf    = X3bf   + 2097152;    // 4096x2048
  u16* P4     = Gbf    + 8388608;    // 4 x 4096 x 512 bf16 split-K partials

  // pack: weight trs + conv2-folded wq2 + conv1-folded cwq1 + inp->bf16
  pack_k<<<1984, 256, 0, stream>>>(inp, ctx_wq, ctx_fc, glb_wq, glb_wk, glb_fc,
                                   mlp_w1, mlp_w2, conv1_w, conv2_w,
                                   wk_t, wq_t, wq2_t, gfc_t, cfc_t, cwq1,
                                   w1_t, w2_t, inp_bf);
  // Wc fold (MFMA): Wc_t[n][e] = sum_m cfc_t[n][m] * cwq1[e][m]
  gemm64_k<<<dim3(8,8),256,0,stream>>>(cfc_t, cwq1, Wc_t, 512, 512);
  // Kg, Vt, ctx in one dispatch; all A = inp_bf (L2-shared); 8-wave blocks
  gemm3_k<<<dim3(4,32,3),512,0,stream>>>(inp_bf, wk_t, Kg, wq_t, Vt, Wc_t, Cbf);
  // LN1: X1 = LN(ctx + inp)
  ln_k<0><<<NT,256,0,stream>>>(Cbf, inp, ln1_g, ln1_b, nullptr,
                               X1bf, nullptr, nullptr);
  // fused Q-gemm (X1 @ Wq2) + attention -> O (Abf)
  qattn_k<<<dim3(8,64),256,0,stream>>>(X1bf, wq2_t, Kg, Vt, Abf);
  // HH = O @ glb_fc
  gemm64_k<<<dim3(8,64),256,0,stream>>>(Abf, gfc_t, Cbf, 512, 512);
  // LN2 (+X1) -> X3bf, fused hn extraction
  ln_k<1><<<NT,256,0,stream>>>(Cbf, X1bf, ln2_g, ln2_b, nullptr,
                               X3bf, nullptr, hn);
  // MLP: w1 128x128 8-wave (512 blocks); w2 split-K4 bf16 partials (512 blocks)
  gemm128_k<1,1><<<dim3(16,32),512,0,stream>>>(X3bf, w1_t, mlp_b1, Gbf, 2048, 512);
  gemm_w2sk<<<dim3(4,32,4),512,0,stream>>>(Gbf, w2_t, P4);
  // LN3: out = LN(P0+P1+P2+P3+b2 + X3)
  ln_k<3><<<NT,256,0,stream>>>(P4, X3bf, ln3_g, ln3_b, mlp_b2,
                               nullptr, out, nullptr);
}